// Round 1
// baseline (2252.399 us; speedup 1.0000x reference)
//
#include <hip/hip_runtime.h>

#define T 512
#define EPS 1e-5f

struct Params {
  const float *x;
  const float *c1w, *c1b, *c2w, *c2b;
  const float *kpw, *kpb, *qpw, *qpb, *vpw, *vpb;
  const float *kng, *knb, *qng, *qnb, *vng, *vnb;
  const float *klw, *klb, *qlw, *qlb, *alw, *alb;
  const float *l1w, *l1b, *l2w, *l2b;
  float *out;
};

__device__ inline float bf2f(unsigned short u) {
  union { unsigned int i; float f; } x; x.i = ((unsigned int)u) << 16; return x.f;
}
__device__ inline unsigned short f2bf(float f) {
  union { float f; unsigned int u; } x; x.f = f;
  unsigned int r = x.u + 0x7fffu + ((x.u >> 16) & 1u);
  return (unsigned short)(r >> 16);
}
__device__ inline float elu_f(float v) { return v > 0.f ? v : __expf(v) - 1.f; }

__device__ inline void ld4bf(const unsigned short* p, float* o) {
  uint2 v = *(const uint2*)p;
  o[0] = bf2f((unsigned short)(v.x & 0xffff));
  o[1] = bf2f((unsigned short)(v.x >> 16));
  o[2] = bf2f((unsigned short)(v.y & 0xffff));
  o[3] = bf2f((unsigned short)(v.y >> 16));
}

// block-wide reduce of (sum, sumsq); on return every thread holds the totals.
__device__ inline void block_reduce2(float& sum, float& sq, float* sRed, int t) {
  int lane = t & 63, wid = t >> 6;
  #pragma unroll
  for (int off = 32; off; off >>= 1) {
    sum += __shfl_down(sum, off, 64);
    sq  += __shfl_down(sq,  off, 64);
  }
  if (lane == 0) { sRed[wid] = sum; sRed[8 + wid] = sq; }
  __syncthreads();
  if (t == 0) {
    float s = 0.f, q = 0.f;
    #pragma unroll
    for (int w = 0; w < 8; w++) { s += sRed[w]; q += sRed[8 + w]; }
    sRed[0] = s; sRed[8] = q;
  }
  __syncthreads();
  sum = sRed[0]; sq = sRed[8];
}

__global__ __launch_bounds__(T) void mhr_fused(Params P) {
  const int b = blockIdx.x;
  const int t = threadIdx.x;

  // K/Q/V (then E in slot 1) as bf16, row stride 200 (padded from 192)
  __shared__ __align__(16) unsigned short sP[3][49 * 200];
  __shared__ __align__(16) float sA0[147 * 52 + 64];  // A0, later F[49][64]; +pad for safe OOB tile reads
  __shared__ __align__(16) float sA1[147 * 52];       // A1 / softmax
  __shared__ __align__(16) float sS[7168];            // staging scratch
  __shared__ float sRed[16];
  __shared__ float sM[64];

  float* xbuf = sS + 6700;   // 147
  float* h1   = sS + 5600;   // 784
  float* tok  = sS + 4480;   // 49*22
  float* wbuf = sS;          // 22*192

  // ---- S0: x -> tokens (conv1, conv2, coords) ----
  for (int i = t; i < 147; i += T) xbuf[i] = P.x[b * 147 + i];
  __syncthreads();
  for (int i = t; i < 49 * 16; i += T) {
    int p = i >> 4, o = i & 15;
    float a = P.c1b[o];
    a += xbuf[p]      * P.c1w[o * 3 + 0];
    a += xbuf[49 + p] * P.c1w[o * 3 + 1];
    a += xbuf[98 + p] * P.c1w[o * 3 + 2];
    h1[p * 16 + o] = fmaxf(a, 0.f);
  }
  __syncthreads();
  for (int i = t; i < 49 * 20; i += T) {
    int p = i / 20, o = i - p * 20;
    float a = P.c2b[o];
    #pragma unroll
    for (int c = 0; c < 16; c++) a += h1[p * 16 + c] * P.c2w[o * 16 + c];
    tok[p * 22 + o] = fmaxf(a, 0.f);
  }
  for (int i = t; i < 49; i += T) {
    tok[i * 22 + 20] = (float)(i % 7) * (1.f / 7.f);
    tok[i * 22 + 21] = (float)(i / 7) * (1.f / 7.f);
  }
  __syncthreads();

  // ---- S1: K/Q/V projections + LN stats ----
  float mu[3], rr[3];
  #pragma unroll
  for (int pr = 0; pr < 3; pr++) {
    const float* w  = pr == 0 ? P.kpw : pr == 1 ? P.qpw : P.vpw;
    const float* bb = pr == 0 ? P.kpb : pr == 1 ? P.qpb : P.vpb;
    for (int i = t; i < 4224; i += T) wbuf[i] = w[i];
    __syncthreads();
    float sum = 0.f, sq = 0.f;
    for (int task = t; task < 1176; task += T) {   // 49 p * 24 j-octets
      int p = task / 24, jo = task - p * 24;
      int j0 = jo * 8;
      float acc[8];
      const float4 b0 = *(const float4*)(bb + j0);
      const float4 b1 = *(const float4*)(bb + j0 + 4);
      acc[0] = b0.x; acc[1] = b0.y; acc[2] = b0.z; acc[3] = b0.w;
      acc[4] = b1.x; acc[5] = b1.y; acc[6] = b1.z; acc[7] = b1.w;
      #pragma unroll 11
      for (int c = 0; c < 22; c++) {
        float tv = tok[p * 22 + c];
        const float4 w0 = *(const float4*)&wbuf[c * 192 + j0];
        const float4 w1 = *(const float4*)&wbuf[c * 192 + j0 + 4];
        acc[0] += tv * w0.x; acc[1] += tv * w0.y; acc[2] += tv * w0.z; acc[3] += tv * w0.w;
        acc[4] += tv * w1.x; acc[5] += tv * w1.y; acc[6] += tv * w1.z; acc[7] += tv * w1.w;
      }
      uint4 pk;
      pk.x = (unsigned)f2bf(acc[0]) | ((unsigned)f2bf(acc[1]) << 16);
      pk.y = (unsigned)f2bf(acc[2]) | ((unsigned)f2bf(acc[3]) << 16);
      pk.z = (unsigned)f2bf(acc[4]) | ((unsigned)f2bf(acc[5]) << 16);
      pk.w = (unsigned)f2bf(acc[6]) | ((unsigned)f2bf(acc[7]) << 16);
      *(uint4*)&sP[pr][p * 200 + j0] = pk;
      #pragma unroll
      for (int k = 0; k < 8; k++) { sum += acc[k]; sq += acc[k] * acc[k]; }
    }
    block_reduce2(sum, sq, sRed, t);   // internal syncs also fence wbuf reuse
    float mean = sum * (1.f / 9408.f);
    mu[pr] = mean;
    rr[pr] = rsqrtf(sq * (1.f / 9408.f) - mean * mean + EPS);
  }

  // ---- S2: normalize K/Q/V in place (gamma/beta from global, L2-resident) ----
  #pragma unroll
  for (int pr = 0; pr < 3; pr++) {
    const float* g  = pr == 0 ? P.kng : pr == 1 ? P.qng : P.vng;
    const float* be = pr == 0 ? P.knb : pr == 1 ? P.qnb : P.vnb;
    float m = mu[pr], r = rr[pr];
    for (int i = t; i < 9408; i += T) {
      int p = i / 192, j = i - p * 192;
      int h = j >> 6, d = j & 63;
      int gi = (h * 49 + p) * 64 + d;
      float v = (bf2f(sP[pr][p * 200 + j]) - m) * r;
      sP[pr][p * 200 + j] = f2bf(v * g[gi] + be[gi]);
    }
  }
  __syncthreads();

  // ---- S3: A0 = elu(Qn@qlw + Kn@klw + (qlb+klb)) ----
  float* sQW = sS;          // [49][68] transposed qlw
  float* sKW = sS + 3332;   // [49][68] transposed klw
  float* cbb = sS + 6664;   // 49 combined biases
  for (int i = t; i < 3136; i += T) {
    int d = i / 49, c = i - d * 49;
    sQW[c * 68 + d] = P.qlw[i];
    sKW[c * 68 + d] = P.klw[i];
  }
  for (int i = t; i < 49; i += T) cbb[i] = P.qlb[i] + P.klb[i];
  __syncthreads();

  const unsigned short* Kn = sP[0];
  const unsigned short* Qn = sP[1];
  for (int task = t; task < 525; task += T) {   // 3h * 25 f-pairs * 7 c-groups
    int h = task / 175;
    int rem = task - h * 175;
    int fp = rem / 7, tc = rem - fp * 7;
    int f0 = fp * 2;
    bool hasF1 = (f0 + 1 < 49);
    int c0 = tc * 7;
    float acc0[7], acc1[7];
    #pragma unroll
    for (int k = 0; k < 7; k++) { float cv = cbb[c0 + k]; acc0[k] = cv; acc1[k] = cv; }
    const unsigned short* q0p = Qn + f0 * 200 + h * 64;
    const unsigned short* k0p = Kn + f0 * 200 + h * 64;
    const unsigned short* q1p = q0p + 200;   // f0==48 reads spill into next array region: harmless, unused
    const unsigned short* k1p = k0p + 200;
    #pragma unroll 4
    for (int dq = 0; dq < 16; dq++) {
      float q0[4], q1[4], kk0[4], kk1[4];
      ld4bf(q0p + dq * 4, q0);
      ld4bf(q1p + dq * 4, q1);
      ld4bf(k0p + dq * 4, kk0);
      ld4bf(k1p + dq * 4, kk1);
      #pragma unroll
      for (int k = 0; k < 7; k++) {
        const float4 wq = *(const float4*)&sQW[(c0 + k) * 68 + dq * 4];
        const float4 wk = *(const float4*)&sKW[(c0 + k) * 68 + dq * 4];
        acc0[k] += q0[0] * wq.x + q0[1] * wq.y + q0[2] * wq.z + q0[3] * wq.w
                 + kk0[0] * wk.x + kk0[1] * wk.y + kk0[2] * wk.z + kk0[3] * wk.w;
        acc1[k] += q1[0] * wq.x + q1[1] * wq.y + q1[2] * wq.z + q1[3] * wq.w
                 + kk1[0] * wk.x + kk1[1] * wk.y + kk1[2] * wk.z + kk1[3] * wk.w;
      }
    }
    float* o0 = sA0 + (h * 49 + f0) * 52 + c0;
    #pragma unroll
    for (int k = 0; k < 7; k++) o0[k] = elu_f(acc0[k]);
    if (hasF1) {
      float* o1 = o0 + 52;
      #pragma unroll
      for (int k = 0; k < 7; k++) o1[k] = elu_f(acc1[k]);
    }
  }
  // zero the 3-col row pads of A0 so S4's quad loop reads zeros there
  for (int i = t; i < 147; i += T) {
    sA0[i * 52 + 49] = 0.f; sA0[i * 52 + 50] = 0.f; sA0[i * 52 + 51] = 0.f;
  }
  __syncthreads();

  // ---- S4: A1 = A0 @ alw + alb ----
  float* sAW = sS;  // [49][52] transposed a_lin_w, zero-padded cols 49..51
  for (int i = t; i < 2401; i += T) {
    int cp = i / 49, c = i - cp * 49;
    sAW[c * 52 + cp] = P.alw[i];
  }
  for (int i = t; i < 49 * 3; i += T) { int c = i / 3, k = i - c * 3; sAW[c * 52 + 49 + k] = 0.f; }
  __syncthreads();

  for (int task = t; task < 525; task += T) {
    int h = task / 175;
    int rem = task - h * 175;
    int fp = rem / 7, tc = rem - fp * 7;
    int f0 = fp * 2;
    bool hasF1 = (f0 + 1 < 49);
    int c0 = tc * 7;
    float acc0[7], acc1[7];
    #pragma unroll
    for (int k = 0; k < 7; k++) { float av = P.alb[c0 + k]; acc0[k] = av; acc1[k] = av; }
    const float* a0p = sA0 + (h * 49 + f0) * 52;
    const float* a1p = a0p + 52;   // fp==24,h==2 reads into pad region: harmless, unused
    #pragma unroll 4
    for (int cq = 0; cq < 13; cq++) {
      float4 x0 = *(const float4*)(a0p + cq * 4);
      float4 x1 = *(const float4*)(a1p + cq * 4);
      #pragma unroll
      for (int k = 0; k < 7; k++) {
        const float4 w = *(const float4*)&sAW[(c0 + k) * 52 + cq * 4];
        acc0[k] += x0.x * w.x + x0.y * w.y + x0.z * w.z + x0.w * w.w;
        acc1[k] += x1.x * w.x + x1.y * w.y + x1.z * w.z + x1.w * w.w;
      }
    }
    float* o0 = sA1 + (h * 49 + f0) * 52 + c0;
    #pragma unroll
    for (int k = 0; k < 7; k++) o0[k] = acc0[k];
    if (hasF1) {
      float* o1 = o0 + 52;
      #pragma unroll
      for (int k = 0; k < 7; k++) o1[k] = acc1[k];
    }
  }
  __syncthreads();

  // ---- S5: row softmax over A1 ----
  for (int r = t; r < 147; r += T) {
    float* row = sA1 + r * 52;
    float m = row[0];
    for (int c = 1; c < 49; c++) m = fmaxf(m, row[c]);
    float s = 0.f;
    for (int c = 0; c < 49; c++) { float e = __expf(row[c] - m); row[c] = e; s += e; }
    float inv = 1.f / s;
    for (int c = 0; c < 49; c++) row[c] *= inv;
  }
  __syncthreads();

  // ---- S6: E = softmax(A1) @ Vn, written as E2[f][h*64+d] bf16 into sP[1] ----
  for (int task = t; task < 1176; task += T) {   // 147 (h,f) * 8 d-octets
    int hf = task >> 3, dg = task & 7;
    int h = hf / 49, f = hf - h * 49;
    int d0 = dg * 8;
    float acc[8];
    #pragma unroll
    for (int k = 0; k < 8; k++) acc[k] = 0.f;
    const float* arow = sA1 + hf * 52;
    const unsigned short* vb = sP[2] + h * 64 + d0;
    for (int c = 0; c < 49; c++) {
      float s = arow[c];
      uint4 v = *(const uint4*)(vb + c * 200);
      acc[0] += s * bf2f((unsigned short)(v.x & 0xffff));
      acc[1] += s * bf2f((unsigned short)(v.x >> 16));
      acc[2] += s * bf2f((unsigned short)(v.y & 0xffff));
      acc[3] += s * bf2f((unsigned short)(v.y >> 16));
      acc[4] += s * bf2f((unsigned short)(v.z & 0xffff));
      acc[5] += s * bf2f((unsigned short)(v.z >> 16));
      acc[6] += s * bf2f((unsigned short)(v.w & 0xffff));
      acc[7] += s * bf2f((unsigned short)(v.w >> 16));
    }
    unsigned short* eo = sP[1] + f * 200 + h * 64 + d0;   // overwrites Q (dead)
    #pragma unroll
    for (int k = 0; k < 8; k++) eo[k] = f2bf(acc[k]);
  }
  __syncthreads();

  // ---- S7: F = relu(E2 @ l1w + l1b), staged in two 96-row halves ----
  float facc[8];
  #pragma unroll
  for (int k = 0; k < 8; k++) facc[k] = 0.f;
  const int f7 = t / 8, dg7 = t & 7, d07 = dg7 * 8;
  #pragma unroll
  for (int half = 0; half < 2; half++) {
    for (int i = t; i < 6144; i += T) sS[i] = P.l1w[half * 6144 + i];
    __syncthreads();
    if (t < 392) {
      const unsigned short* erow = sP[1] + f7 * 200 + half * 96;
      #pragma unroll 4
      for (int jq = 0; jq < 24; jq++) {
        float e4[4];
        ld4bf(erow + jq * 4, e4);
        #pragma unroll
        for (int jj = 0; jj < 4; jj++) {
          float ev = e4[jj];
          const float4 wlo = *(const float4*)&sS[(jq * 4 + jj) * 64 + d07];
          const float4 whi = *(const float4*)&sS[(jq * 4 + jj) * 64 + d07 + 4];
          facc[0] += ev * wlo.x; facc[1] += ev * wlo.y; facc[2] += ev * wlo.z; facc[3] += ev * wlo.w;
          facc[4] += ev * whi.x; facc[5] += ev * whi.y; facc[6] += ev * whi.z; facc[7] += ev * whi.w;
        }
      }
    }
    __syncthreads();
  }
  if (t < 392) {
    float* Fr = sA0 + f7 * 64 + d07;   // reuse A0 region as F[49][64]
    #pragma unroll
    for (int k = 0; k < 8; k++) Fr[k] = fmaxf(facc[k] + P.l1b[d07 + k], 0.f);
  }
  __syncthreads();

  // ---- S8: LN(F) (no affine) -> column max -> lin2 -> elu ----
  float s8 = 0.f, q8 = 0.f;
  for (int i = t; i < 3136; i += T) { float v = sA0[i]; s8 += v; q8 += v * v; }
  block_reduce2(s8, q8, sRed, t);
  float m8 = s8 * (1.f / 3136.f);
  float r8 = rsqrtf(q8 * (1.f / 3136.f) - m8 * m8 + EPS);
  if (t < 64) {
    float mx = -1e30f;
    for (int f = 0; f < 49; f++) mx = fmaxf(mx, sA0[f * 64 + t]);
    sM[t] = (mx - m8) * r8;   // rstd > 0 => max commutes with normalize
  }
  __syncthreads();
  if (t < 5) {
    float a = P.l2b[t];
    #pragma unroll 16
    for (int d = 0; d < 64; d++) a += sM[d] * P.l2w[d * 5 + t];
    P.out[b * 5 + t] = elu_f(a);
  }
}

extern "C" void kernel_launch(void* const* d_in, const int* in_sizes, int n_in,
                              void* d_out, int out_size, void* d_ws, size_t ws_size,
                              hipStream_t stream) {
  Params P;
  P.x   = (const float*)d_in[0];
  P.c1w = (const float*)d_in[1];  P.c1b = (const float*)d_in[2];
  P.c2w = (const float*)d_in[3];  P.c2b = (const float*)d_in[4];
  P.kpw = (const float*)d_in[5];  P.kpb = (const float*)d_in[6];
  P.qpw = (const float*)d_in[7];  P.qpb = (const float*)d_in[8];
  P.vpw = (const float*)d_in[9];  P.vpb = (const float*)d_in[10];
  P.kng = (const float*)d_in[11]; P.knb = (const float*)d_in[12];
  P.qng = (const float*)d_in[13]; P.qnb = (const float*)d_in[14];
  P.vng = (const float*)d_in[15]; P.vnb = (const float*)d_in[16];
  P.klw = (const float*)d_in[17]; P.klb = (const float*)d_in[18];
  P.qlw = (const float*)d_in[19]; P.qlb = (const float*)d_in[20];
  P.alw = (const float*)d_in[21]; P.alb = (const float*)d_in[22];
  P.l1w = (const float*)d_in[23]; P.l1b = (const float*)d_in[24];
  P.l2w = (const float*)d_in[25]; P.l2b = (const float*)d_in[26];
  P.out = (float*)d_out;

  int B = in_sizes[0] / 147;   // [B,3,7,7]
  hipLaunchKernelGGL(mhr_fused, dim3(B), dim3(T), 0, stream, P);
}

// Round 3
// 1743.136 us; speedup vs baseline: 1.2922x; 1.2922x over previous
//
#include <hip/hip_runtime.h>

#define T 1024
#define EPS 1e-5f

struct Params {
  const float *x;
  const float *c1w, *c1b, *c2w, *c2b;
  const float *kpw, *kpb, *qpw, *qpb, *vpw, *vpb;
  const float *kng, *knb, *qng, *qnb, *vng, *vnb;
  const float *klw, *klb, *qlw, *qlb, *alw, *alb;
  const float *l1w, *l1b, *l2w, *l2b;
  float *out;
};

__device__ inline float bf2f(unsigned short u) {
  union { unsigned int i; float f; } x; x.i = ((unsigned int)u) << 16; return x.f;
}
__device__ inline unsigned short f2bf(float f) {
  union { float f; unsigned int u; } x; x.f = f;
  unsigned int r = x.u + 0x7fffu + ((x.u >> 16) & 1u);
  return (unsigned short)(r >> 16);
}
__device__ inline float elu_f(float v) { return v > 0.f ? v : __expf(v) - 1.f; }

__device__ inline void ld4bf(const unsigned short* p, float* o) {
  uint2 v = *(const uint2*)p;
  o[0] = bf2f((unsigned short)(v.x & 0xffff));
  o[1] = bf2f((unsigned short)(v.x >> 16));
  o[2] = bf2f((unsigned short)(v.y & 0xffff));
  o[3] = bf2f((unsigned short)(v.y >> 16));
}

// block-wide reduce of (sum, sumsq) for 16 waves; all threads get totals.
__device__ inline void block_reduce2(float& sum, float& sq, float* sRed, int t) {
  int lane = t & 63, wid = t >> 6;   // wid 0..15
  #pragma unroll
  for (int off = 32; off; off >>= 1) {
    sum += __shfl_down(sum, off, 64);
    sq  += __shfl_down(sq,  off, 64);
  }
  if (lane == 0) { sRed[wid] = sum; sRed[16 + wid] = sq; }
  __syncthreads();
  if (t == 0) {
    float s = 0.f, q = 0.f;
    #pragma unroll
    for (int w = 0; w < 16; w++) { s += sRed[w]; q += sRed[16 + w]; }
    sRed[0] = s; sRed[16] = q;
  }
  __syncthreads();
  sum = sRed[0]; sq = sRed[16];
}

__global__ __launch_bounds__(T) void mhr_fused(Params P) {
  const int b = blockIdx.x;
  const int t = threadIdx.x;

  // K/Q/V (then E in slot 1) as bf16, row stride 200 (padded from 192)
  __shared__ __align__(16) unsigned short sP[3][49 * 200];
  __shared__ __align__(16) float sA0[147 * 52 + 64];  // A0 partial0 / A0 / F[49][64]
  __shared__ __align__(16) float sA1[147 * 52];       // A0 partial1 / A1 / softmax
  __shared__ __align__(16) float sS[7168];            // staging scratch
  __shared__ float sRed[32];
  __shared__ float sM[64];

  float* xbuf = sS + 6700;   // 147
  float* h1   = sS + 5600;   // 784
  float* tokT = sS + 4480;   // [22][49] transposed tokens
  float* wbuf = sS;          // 22*192

  // ---- S0: x -> tokens (conv1, conv2, coords), stored TRANSPOSED [c][p] ----
  for (int i = t; i < 147; i += T) xbuf[i] = P.x[b * 147 + i];
  __syncthreads();
  for (int i = t; i < 49 * 16; i += T) {
    int p = i >> 4, o = i & 15;
    float a = P.c1b[o];
    a += xbuf[p]      * P.c1w[o * 3 + 0];
    a += xbuf[49 + p] * P.c1w[o * 3 + 1];
    a += xbuf[98 + p] * P.c1w[o * 3 + 2];
    h1[p * 16 + o] = fmaxf(a, 0.f);
  }
  __syncthreads();
  for (int i = t; i < 49 * 20; i += T) {
    int p = i / 20, o = i - p * 20;
    float a = P.c2b[o];
    #pragma unroll
    for (int c = 0; c < 16; c++) a += h1[p * 16 + c] * P.c2w[o * 16 + c];
    tokT[o * 49 + p] = fmaxf(a, 0.f);
  }
  for (int i = t; i < 49; i += T) {
    tokT[20 * 49 + i] = (float)(i % 7) * (1.f / 7.f);
    tokT[21 * 49 + i] = (float)(i / 7) * (1.f / 7.f);
  }
  __syncthreads();

  // ---- S1: K/Q/V projections + LN stats. task=(jo,p): weights broadcast ----
  float mu[3], rr[3];
  #pragma unroll
  for (int pr = 0; pr < 3; pr++) {
    const float* w  = pr == 0 ? P.kpw : pr == 1 ? P.qpw : P.vpw;
    const float* bb = pr == 0 ? P.kpb : pr == 1 ? P.qpb : P.vpb;
    for (int i = t; i < 4224; i += T) wbuf[i] = w[i];
    __syncthreads();
    float sum = 0.f, sq = 0.f;
    for (int task = t; task < 1176; task += T) {   // 24 jo * 49 p
      int jo = task / 49, p = task - jo * 49;
      int j0 = jo * 8;
      float acc[8];
      const float4 b0 = *(const float4*)(bb + j0);
      const float4 b1 = *(const float4*)(bb + j0 + 4);
      acc[0] = b0.x; acc[1] = b0.y; acc[2] = b0.z; acc[3] = b0.w;
      acc[4] = b1.x; acc[5] = b1.y; acc[6] = b1.z; acc[7] = b1.w;
      #pragma unroll 11
      for (int c = 0; c < 22; c++) {
        float tv = tokT[c * 49 + p];
        const float4 w0 = *(const float4*)&wbuf[c * 192 + j0];
        const float4 w1 = *(const float4*)&wbuf[c * 192 + j0 + 4];
        acc[0] += tv * w0.x; acc[1] += tv * w0.y; acc[2] += tv * w0.z; acc[3] += tv * w0.w;
        acc[4] += tv * w1.x; acc[5] += tv * w1.y; acc[6] += tv * w1.z; acc[7] += tv * w1.w;
      }
      uint4 pk;
      pk.x = (unsigned)f2bf(acc[0]) | ((unsigned)f2bf(acc[1]) << 16);
      pk.y = (unsigned)f2bf(acc[2]) | ((unsigned)f2bf(acc[3]) << 16);
      pk.z = (unsigned)f2bf(acc[4]) | ((unsigned)f2bf(acc[5]) << 16);
      pk.w = (unsigned)f2bf(acc[6]) | ((unsigned)f2bf(acc[7]) << 16);
      *(uint4*)&sP[pr][p * 200 + j0] = pk;
      #pragma unroll
      for (int k = 0; k < 8; k++) { sum += acc[k]; sq += acc[k] * acc[k]; }
    }
    block_reduce2(sum, sq, sRed, t);   // internal syncs also fence wbuf reuse
    float mean = sum * (1.f / 9408.f);
    mu[pr] = mean;
    rr[pr] = rsqrtf(sq * (1.f / 9408.f) - mean * mean + EPS);
  }

  // ---- S2: normalize K/Q/V in place, 4 elems/thread ----
  #pragma unroll
  for (int pr = 0; pr < 3; pr++) {
    const float* g  = pr == 0 ? P.kng : pr == 1 ? P.qng : P.vng;
    const float* be = pr == 0 ? P.knb : pr == 1 ? P.qnb : P.vnb;
    float m = mu[pr], r = rr[pr];
    for (int task = t; task < 2352; task += T) {   // 49 p * 48 j-quads
      int p = task / 48, jq = task - p * 48;
      int j0 = jq * 4;
      int h = j0 >> 6, d = j0 & 63;
      int gi = (h * 49 + p) * 64 + d;
      unsigned short* sp = &sP[pr][p * 200 + j0];
      uint2 v = *(const uint2*)sp;
      float4 g4 = *(const float4*)&g[gi];
      float4 b4 = *(const float4*)&be[gi];
      float v0 = (bf2f((unsigned short)(v.x & 0xffff)) - m) * r * g4.x + b4.x;
      float v1 = (bf2f((unsigned short)(v.x >> 16))    - m) * r * g4.y + b4.y;
      float v2 = (bf2f((unsigned short)(v.y & 0xffff)) - m) * r * g4.z + b4.z;
      float v3 = (bf2f((unsigned short)(v.y >> 16))    - m) * r * g4.w + b4.w;
      uint2 o;
      o.x = (unsigned)f2bf(v0) | ((unsigned)f2bf(v1) << 16);
      o.y = (unsigned)f2bf(v2) | ((unsigned)f2bf(v3) << 16);
      *(uint2*)sp = o;
    }
  }

  // ---- S3: A0 = elu(Qn@qlw + Kn@klw + bias), split in two d-halves ----
  float* sQW = sS;          // [49][68] transposed qlw
  float* sKW = sS + 3332;   // [49][68] transposed klw
  float* cbb = sS + 6664;   // 49 combined biases
  for (int i = t; i < 3136; i += T) {
    int d = i / 49, c = i - d * 49;
    sQW[c * 68 + d] = P.qlw[i];
    sKW[c * 68 + d] = P.klw[i];
  }
  for (int i = t; i < 49; i += T) cbb[i] = P.qlb[i] + P.klb[i];
  __syncthreads();

  const unsigned short* Kn = sP[0];
  const unsigned short* Qn = sP[1];
  for (int task = t; task < 1050; task += T) {   // 2 dhalf * 3h * 25 fp * 7 tc
    int dhalf = task / 525;
    int rem = task - dhalf * 525;
    int h = rem / 175;
    int rem2 = rem - h * 175;
    int fp = rem2 / 7, tc = rem2 - fp * 7;
    int f0 = fp * 2;
    bool hasF1 = (f0 + 1 < 49);
    int c0 = tc * 7;
    float acc0[7], acc1[7];
    #pragma unroll
    for (int k = 0; k < 7; k++) {
      float cv = dhalf ? 0.f : cbb[c0 + k];
      acc0[k] = cv; acc1[k] = cv;
    }
    const unsigned short* q0p = Qn + f0 * 200 + h * 64;
    const unsigned short* k0p = Kn + f0 * 200 + h * 64;
    const unsigned short* q1p = q0p + 200;   // f0==48 spills into next region: unused
    const unsigned short* k1p = k0p + 200;
    int dq0 = dhalf * 8;
    #pragma unroll 4
    for (int dqi = 0; dqi < 8; dqi++) {
      int dq = dq0 + dqi;
      float q0[4], q1[4], kk0[4], kk1[4];
      ld4bf(q0p + dq * 4, q0);
      ld4bf(q1p + dq * 4, q1);
      ld4bf(k0p + dq * 4, kk0);
      ld4bf(k1p + dq * 4, kk1);
      #pragma unroll
      for (int k = 0; k < 7; k++) {
        const float4 wq = *(const float4*)&sQW[(c0 + k) * 68 + dq * 4];
        const float4 wk = *(const float4*)&sKW[(c0 + k) * 68 + dq * 4];
        acc0[k] += q0[0] * wq.x + q0[1] * wq.y + q0[2] * wq.z + q0[3] * wq.w
                 + kk0[0] * wk.x + kk0[1] * wk.y + kk0[2] * wk.z + kk0[3] * wk.w;
        acc1[k] += q1[0] * wq.x + q1[1] * wq.y + q1[2] * wq.z + q1[3] * wq.w
                 + kk1[0] * wk.x + kk1[1] * wk.y + kk1[2] * wk.z + kk1[3] * wk.w;
      }
    }
    float* dst = (dhalf ? sA1 : sA0) + (h * 49 + f0) * 52 + c0;
    #pragma unroll
    for (int k = 0; k < 7; k++) dst[k] = acc0[k];
    if (hasF1) {
      #pragma unroll
      for (int k = 0; k < 7; k++) dst[52 + k] = acc1[k];
    }
  }
  __syncthreads();
  // merge halves + elu; zero the 3 pad cols. Also stage a_lin_w (disjoint LDS).
  for (int i = t; i < 7644; i += T) {
    int c = i % 52;
    sA0[i] = (c < 49) ? elu_f(sA0[i] + sA1[i]) : 0.f;
  }
  float* sAW = sS;  // [49][52] transposed a_lin_w, zero-padded cols 49..51
  for (int i = t; i < 2401; i += T) {
    int cp = i / 49, c = i - cp * 49;
    sAW[c * 52 + cp] = P.alw[i];
  }
  for (int i = t; i < 147; i += T) { int c = i / 3, k = i - c * 3; sAW[c * 52 + 49 + k] = 0.f; }
  __syncthreads();

  // ---- S4: A1 = A0 @ alw + alb, split in two cq-halves ----
  // partial-1 scratch: 7644 floats = 30576 B. K (sP[0], 19600 B) AND Q (sP[1],
  // 19600 B) are both dead after S3 and contiguous -> 39200 B available.
  float* pB = (float*)(void*)sP[0];
  for (int task = t; task < 1050; task += T) {
    int chalf = task / 525;
    int rem = task - chalf * 525;
    int h = rem / 175;
    int rem2 = rem - h * 175;
    int fp = rem2 / 7, tc = rem2 - fp * 7;
    int f0 = fp * 2;
    bool hasF1 = (f0 + 1 < 49);
    int c0 = tc * 7;
    float acc0[7], acc1[7];
    #pragma unroll
    for (int k = 0; k < 7; k++) {
      float av = chalf ? 0.f : P.alb[c0 + k];
      acc0[k] = av; acc1[k] = av;
    }
    const float* a0p = sA0 + (h * 49 + f0) * 52;
    const float* a1p = a0p + 52;   // fp==24,h==2 reads pad region: unused
    int cqs = chalf ? 7 : 0, cqe = chalf ? 13 : 7;
    #pragma unroll 3
    for (int cq = cqs; cq < cqe; cq++) {
      float4 x0 = *(const float4*)(a0p + cq * 4);
      float4 x1 = *(const float4*)(a1p + cq * 4);
      #pragma unroll
      for (int k = 0; k < 7; k++) {
        const float4 w = *(const float4*)&sAW[(c0 + k) * 52 + cq * 4];
        acc0[k] += x0.x * w.x + x0.y * w.y + x0.z * w.z + x0.w * w.w;
        acc1[k] += x1.x * w.x + x1.y * w.y + x1.z * w.z + x1.w * w.w;
      }
    }
    float* dst = (chalf ? pB : sA1) + (h * 49 + f0) * 52 + c0;
    #pragma unroll
    for (int k = 0; k < 7; k++) dst[k] = acc0[k];
    if (hasF1) {
      #pragma unroll
      for (int k = 0; k < 7; k++) dst[52 + k] = acc1[k];
    }
  }
  __syncthreads();
  for (int i = t; i < 7644; i += T) {
    int c = i % 52;
    if (c < 49) sA1[i] = sA1[i] + pB[i];
  }
  __syncthreads();

  // ---- S5: row softmax over A1 ----
  for (int r = t; r < 147; r += T) {
    float* row = sA1 + r * 52;
    float m = row[0];
    for (int c = 1; c < 49; c++) m = fmaxf(m, row[c]);
    float s = 0.f;
    for (int c = 0; c < 49; c++) { float e = __expf(row[c] - m); row[c] = e; s += e; }
    float inv = 1.f / s;
    for (int c = 0; c < 49; c++) row[c] *= inv;
  }
  __syncthreads();

  // ---- S6: E = softmax(A1) @ Vn -> E2[f][h*64+d] bf16 into sP[1] ----
  for (int task = t; task < 1176; task += T) {   // 147 (h,f) * 8 d-octets
    int hf = task >> 3, dg = task & 7;
    int h = hf / 49, f = hf - h * 49;
    int d0 = dg * 8;
    float acc[8];
    #pragma unroll
    for (int k = 0; k < 8; k++) acc[k] = 0.f;
    const float* arow = sA1 + hf * 52;
    const unsigned short* vb = sP[2] + h * 64 + d0;
    for (int c = 0; c < 49; c++) {
      float s = arow[c];
      uint4 v = *(const uint4*)(vb + c * 200);
      acc[0] += s * bf2f((unsigned short)(v.x & 0xffff));
      acc[1] += s * bf2f((unsigned short)(v.x >> 16));
      acc[2] += s * bf2f((unsigned short)(v.y & 0xffff));
      acc[3] += s * bf2f((unsigned short)(v.y >> 16));
      acc[4] += s * bf2f((unsigned short)(v.z & 0xffff));
      acc[5] += s * bf2f((unsigned short)(v.z >> 16));
      acc[6] += s * bf2f((unsigned short)(v.w & 0xffff));
      acc[7] += s * bf2f((unsigned short)(v.w >> 16));
    }
    unsigned short* eo = sP[1] + f * 200 + h * 64 + d0;   // overwrites Q/pB (dead)
    uint4 pk;
    pk.x = (unsigned)f2bf(acc[0]) | ((unsigned)f2bf(acc[1]) << 16);
    pk.y = (unsigned)f2bf(acc[2]) | ((unsigned)f2bf(acc[3]) << 16);
    pk.z = (unsigned)f2bf(acc[4]) | ((unsigned)f2bf(acc[5]) << 16);
    pk.w = (unsigned)f2bf(acc[6]) | ((unsigned)f2bf(acc[7]) << 16);
    *(uint4*)eo = pk;
  }
  __syncthreads();

  // ---- S7: F = relu(E2 @ l1w + l1b), staged in two 96-row halves, d-quads ----
  const int f7 = t >> 4, d07 = (t & 15) * 4;
  float facc[4] = {0.f, 0.f, 0.f, 0.f};
  #pragma unroll
  for (int half = 0; half < 2; half++) {
    for (int i = t; i < 6144; i += T) sS[i] = P.l1w[half * 6144 + i];
    __syncthreads();
    if (t < 784) {
      const unsigned short* erow = sP[1] + f7 * 200 + half * 96;
      #pragma unroll 4
      for (int jq = 0; jq < 24; jq++) {
        float e4[4];
        ld4bf(erow + jq * 4, e4);
        #pragma unroll
        for (int jj = 0; jj < 4; jj++) {
          const float4 w = *(const float4*)&sS[(jq * 4 + jj) * 64 + d07];
          facc[0] += e4[jj] * w.x; facc[1] += e4[jj] * w.y;
          facc[2] += e4[jj] * w.z; facc[3] += e4[jj] * w.w;
        }
      }
    }
    __syncthreads();
  }
  if (t < 784) {
    const float4 b4 = *(const float4*)&P.l1b[d07];
    float* Fr = sA0 + f7 * 64 + d07;   // reuse A0 region as F[49][64]
    Fr[0] = fmaxf(facc[0] + b4.x, 0.f);
    Fr[1] = fmaxf(facc[1] + b4.y, 0.f);
    Fr[2] = fmaxf(facc[2] + b4.z, 0.f);
    Fr[3] = fmaxf(facc[3] + b4.w, 0.f);
  }
  __syncthreads();

  // ---- S8: LN(F) (no affine) -> column max -> lin2 -> elu ----
  float s8 = 0.f, q8 = 0.f;
  for (int i = t; i < 3136; i += T) { float v = sA0[i]; s8 += v; q8 += v * v; }
  block_reduce2(s8, q8, sRed, t);
  float m8 = s8 * (1.f / 3136.f);
  float r8 = rsqrtf(q8 * (1.f / 3136.f) - m8 * m8 + EPS);
  if (t < 64) {
    float mx = -1e30f;
    for (int f = 0; f < 49; f++) mx = fmaxf(mx, sA0[f * 64 + t]);
    sM[t] = (mx - m8) * r8;   // rstd > 0 => max commutes with normalize
  }
  __syncthreads();
  if (t < 5) {
    float a = P.l2b[t];
    #pragma unroll 16
    for (int d = 0; d < 64; d++) a += sM[d] * P.l2w[d * 5 + t];
    P.out[b * 5 + t] = elu_f(a);
  }
}

extern "C" void kernel_launch(void* const* d_in, const int* in_sizes, int n_in,
                              void* d_out, int out_size, void* d_ws, size_t ws_size,
                              hipStream_t stream) {
  Params P;
  P.x   = (const float*)d_in[0];
  P.c1w = (const float*)d_in[1];  P.c1b = (const float*)d_in[2];
  P.c2w = (const float*)d_in[3];  P.c2b = (const float*)d_in[4];
  P.kpw = (const float*)d_in[5];  P.kpb = (const float*)d_in[6];
  P.qpw = (const float*)d_in[7];  P.qpb = (const float*)d_in[8];
  P.vpw = (const float*)d_in[9];  P.vpb = (const float*)d_in[10];
  P.kng = (const float*)d_in[11]; P.knb = (const float*)d_in[12];
  P.qng = (const float*)d_in[13]; P.qnb = (const float*)d_in[14];
  P.vng = (const float*)d_in[15]; P.vnb = (const float*)d_in[16];
  P.klw = (const float*)d_in[17]; P.klb = (const float*)d_in[18];
  P.qlw = (const float*)d_in[19]; P.qlb = (const float*)d_in[20];
  P.alw = (const float*)d_in[21]; P.alb = (const float*)d_in[22];
  P.l1w = (const float*)d_in[23]; P.l1b = (const float*)d_in[24];
  P.l2w = (const float*)d_in[25]; P.l2b = (const float*)d_in[26];
  P.out = (float*)d_out;

  int B = in_sizes[0] / 147;   // [B,3,7,7]
  hipLaunchKernelGGL(mhr_fused, dim3(B), dim3(T), 0, stream, P);
}

// Round 4
// 1014.187 us; speedup vs baseline: 2.2209x; 1.7188x over previous
//
#include <hip/hip_runtime.h>

#define T 1024
#define EPS 1e-5f

typedef _Float16 f16x8 __attribute__((ext_vector_type(8)));
typedef float f32x4 __attribute__((ext_vector_type(4)));

#define MFMA16(a, b, c) __builtin_amdgcn_mfma_f32_16x16x32_f16((a), (b), (c), 0, 0, 0)

struct Params {
  const float *x;
  const float *c1w, *c1b, *c2w, *c2b;
  const float *kpw, *kpb, *qpw, *qpb, *vpw, *vpb;
  const float *kng, *knb, *qng, *qnb, *vng, *vnb;
  const float *klw, *klb, *qlw, *qlb, *alw, *alb;
  const float *l1w, *l1b, *l2w, *l2b;
  float *out;
};

__device__ inline float elu_f(float v) { return v > 0.f ? v : __expf(v) - 1.f; }

// block-wide reduce of (sum, sumsq) for 16 waves; all threads get totals.
__device__ inline void block_reduce2(float& sum, float& sq, float* sRed, int t) {
  int lane = t & 63, wid = t >> 6;   // wid 0..15
  #pragma unroll
  for (int off = 32; off; off >>= 1) {
    sum += __shfl_down(sum, off, 64);
    sq  += __shfl_down(sq,  off, 64);
  }
  if (lane == 0) { sRed[wid] = sum; sRed[16 + wid] = sq; }
  __syncthreads();
  if (t == 0) {
    float s = 0.f, q = 0.f;
    #pragma unroll
    for (int w = 0; w < 16; w++) { s += sRed[w]; q += sRed[16 + w]; }
    sRed[0] = s; sRed[16] = q;
  }
  __syncthreads();
  sum = sRed[0]; sq = sRed[16];
}

// MFMA fragment conventions (16x16x32, fp16 in / fp32 out):
//   A-frag: lane l holds A[row = l&15][k = (l>>4)*8 + e], e=0..7  (row-major [M][K])
//   B-frag: lane l holds B[k = (l>>4)*8 + e][col = l&15]          (loaded from BT[N][K] row-major)
//   C/D  : lane l, reg r -> D[row = (l>>4)*4 + r][col = l&15]     (m89-verified)
// All LDS f16 tiles are "[rows][K] row-major"; strides 40/72/200 f16 give
// conflict-free ds_read_b128 (8-lane groups cover all 32 banks disjointly).

__global__ __launch_bounds__(T) void mhr_fused(Params P) {
  const int b = blockIdx.x;
  const int t = threadIdx.x;
  const int wid = t >> 6, l = t & 63, lr = l & 15, lk = l >> 4;

  __shared__ __align__(16) _Float16 sKQ[2][9800];  // Kn/Qn [49][200]; later A1 [3][64][72]
  __shared__ __align__(16) _Float16 sVT[13824];    // V^T [192][72]; later F fp32 [49][68]
  __shared__ __align__(16) _Float16 sA0[13824];    // A0 [3][64][72]; later E [49][200]
  __shared__ __align__(16) _Float16 sW[12800];     // weight staging (max: l1wT 64x200)
  __shared__ __align__(16) _Float16 sTok[2560];    // tokens A-tile [64][40]
  __shared__ float cbb[49];
  __shared__ float sRed[32];
  __shared__ float sM[64];

  // ---- P0: x -> tokens, directly as fp16 A-tile [64][40], zero-padded ----
  float* xb = (float*)sW;        // 147 floats
  float* h1 = (float*)sW + 160;  // 784 floats
  for (int i = t; i < 640; i += T) ((unsigned*)sTok)[i] = 0u;  // zero whole tile
  for (int i = t; i < 147; i += T) xb[i] = P.x[b * 147 + i];
  __syncthreads();
  for (int i = t; i < 784; i += T) {
    int p = i >> 4, o = i & 15;
    float a = P.c1b[o] + xb[p] * P.c1w[o * 3] + xb[49 + p] * P.c1w[o * 3 + 1]
            + xb[98 + p] * P.c1w[o * 3 + 2];
    h1[p * 16 + o] = fmaxf(a, 0.f);
  }
  __syncthreads();
  for (int i = t; i < 980; i += T) {
    int p = i / 20, o = i - p * 20;
    float a = P.c2b[o];
    #pragma unroll
    for (int c = 0; c < 16; c++) a += h1[p * 16 + c] * P.c2w[o * 16 + c];
    sTok[p * 40 + o] = (_Float16)fmaxf(a, 0.f);
  }
  for (int i = t; i < 49; i += T) {
    sTok[i * 40 + 20] = (_Float16)((float)(i % 7) * (1.f / 7.f));
    sTok[i * 40 + 21] = (_Float16)((float)(i / 7) * (1.f / 7.f));
  }
  __syncthreads();

  // ---- P1: K/Q/V projections via MFMA + LN (V produced transposed) ----
  #pragma unroll 1
  for (int pr = 0; pr < 3; pr++) {
    const float* w  = pr == 0 ? P.kpw : pr == 1 ? P.qpw : P.vpw;
    const float* bb = pr == 0 ? P.kpb : pr == 1 ? P.qpb : P.vpb;
    // stage W^T [192][40], k-pad (c 22..39) zeroed
    for (int i = t; i < 7680; i += T) {
      int j = i / 40, c = i - j * 40;
      sW[i] = (c < 22) ? (_Float16)w[c * 192 + j] : (_Float16)0.f;
    }
    __syncthreads();
    f32x4 acc[3];
    float sum = 0.f, sq = 0.f;
    if (pr < 2) {
      // D[p][j]: 4 m-tiles x 12 n-tiles
      #pragma unroll
      for (int i = 0; i < 3; i++) {
        int tt = wid + 16 * i;
        int tm = tt / 12, tn = tt - tm * 12;
        f16x8 a  = *(const f16x8*)&sTok[(tm * 16 + lr) * 40 + lk * 8];
        f16x8 bf = *(const f16x8*)&sW[(tn * 16 + lr) * 40 + lk * 8];
        f32x4 c = {0.f, 0.f, 0.f, 0.f};
        c = MFMA16(a, bf, c);
        float bj = bb[tn * 16 + lr];
        #pragma unroll
        for (int r = 0; r < 4; r++) {
          int p = tm * 16 + lk * 4 + r;
          float v = c[r] + bj;
          c[r] = v;
          if (p < 49) { sum += v; sq += v * v; }
        }
        acc[i] = c;
      }
    } else {
      // V^T: D[j][p]: 12 m-tiles (j) x 4 n-tiles (p), operands swapped
      #pragma unroll
      for (int i = 0; i < 3; i++) {
        int tt = wid + 16 * i;
        int tm = tt >> 2, tn = tt & 3;
        f16x8 a  = *(const f16x8*)&sW[(tm * 16 + lr) * 40 + lk * 8];
        f16x8 bf = *(const f16x8*)&sTok[(tn * 16 + lr) * 40 + lk * 8];
        f32x4 c = {0.f, 0.f, 0.f, 0.f};
        c = MFMA16(a, bf, c);
        int p = tn * 16 + lr;
        bool colv = p < 49;
        #pragma unroll
        for (int r = 0; r < 4; r++) {
          int j = tm * 16 + lk * 4 + r;
          float v = c[r] + bb[j];
          c[r] = v;
          if (colv) { sum += v; sq += v * v; }
        }
        acc[i] = c;
      }
    }
    block_reduce2(sum, sq, sRed, t);
    float mean = sum * (1.f / 9408.f);
    float rstd = rsqrtf(sq * (1.f / 9408.f) - mean * mean + EPS);
    const float* g  = pr == 0 ? P.kng : pr == 1 ? P.qng : P.vng;
    const float* be = pr == 0 ? P.knb : pr == 1 ? P.qnb : P.vnb;
    if (pr < 2) {
      #pragma unroll
      for (int i = 0; i < 3; i++) {
        int tt = wid + 16 * i;
        int tm = tt / 12, tn = tt - tm * 12;
        int j = tn * 16 + lr, h = j >> 6, d = j & 63;
        #pragma unroll
        for (int r = 0; r < 4; r++) {
          int p = tm * 16 + lk * 4 + r;
          if (p < 49) {
            int gi = (h * 49 + p) * 64 + d;
            sKQ[pr][p * 200 + j] = (_Float16)((acc[i][r] - mean) * rstd * g[gi] + be[gi]);
          }
        }
      }
    } else {
      #pragma unroll
      for (int i = 0; i < 3; i++) {
        int tt = wid + 16 * i;
        int tm = tt >> 2, tn = tt & 3;
        int p = tn * 16 + lr;
        if (p < 49) {
          #pragma unroll
          for (int r = 0; r < 4; r++) {
            int j = tm * 16 + lk * 4 + r;
            int gi = ((j >> 6) * 49 + p) * 64 + (j & 63);
            sVT[j * 72 + p] = (_Float16)((acc[i][r] - mean) * rstd * g[gi] + be[gi]);
          }
        }
      }
      // zero V^T k-pad cols (p 49..63) — disjoint from the writes above
      for (int i2 = t; i2 < 2880; i2 += T) {
        int j = i2 / 15, c = 49 + (i2 - (i2 / 15) * 15);
        sVT[j * 72 + c] = (_Float16)0.f;
      }
    }
    __syncthreads();
  }

  // ---- P2 (S3): A0 = elu(Qn@qlw + Kn@klw + bias), MFMA ----
  for (int i = t; i < 3136; i += T) {
    int d = i / 49, c = i - d * 49;
    sW[c * 72 + d]        = (_Float16)P.qlw[i];   // qlwT [49->64][72], k=d (64 exact)
    sW[4608 + c * 72 + d] = (_Float16)P.klw[i];   // klwT
  }
  for (int i = t; i < 49; i += T) cbb[i] = P.qlb[i] + P.klb[i];
  __syncthreads();
  #pragma unroll
  for (int i = 0; i < 3; i++) {
    int tt = wid + 16 * i;
    int h = tt >> 4, r16 = tt & 15, tmf = r16 >> 2, tnc = r16 & 3;
    f32x4 c = {0.f, 0.f, 0.f, 0.f};
    #pragma unroll
    for (int ks = 0; ks < 2; ks++) {
      f16x8 aQ = *(const f16x8*)&sKQ[1][(tmf * 16 + lr) * 200 + h * 64 + ks * 32 + lk * 8];
      f16x8 bQ = *(const f16x8*)&sW[(tnc * 16 + lr) * 72 + ks * 32 + lk * 8];
      c = MFMA16(aQ, bQ, c);
      f16x8 aK = *(const f16x8*)&sKQ[0][(tmf * 16 + lr) * 200 + h * 64 + ks * 32 + lk * 8];
      f16x8 bK = *(const f16x8*)&sW[4608 + (tnc * 16 + lr) * 72 + ks * 32 + lk * 8];
      c = MFMA16(aK, bK, c);
    }
    int cc = tnc * 16 + lr;
    if (cc < 49) {
      float cb = cbb[cc];
      #pragma unroll
      for (int r = 0; r < 4; r++) {
        int f = tmf * 16 + lk * 4 + r;
        if (f < 49) sA0[h * 4608 + f * 72 + cc] = (_Float16)elu_f(c[r] + cb);
      }
    }
  }
  // zero A0 k-pad cols (c 49..63) for valid rows
  for (int i = t; i < 2205; i += T) {
    int h = i / 735, r2 = i - h * 735, f = r2 / 15, cc = 49 + (r2 - (r2 / 15) * 15);
    sA0[h * 4608 + f * 72 + cc] = (_Float16)0.f;
  }
  __syncthreads();

  // ---- P3 (S4): A1 = A0 @ alw + alb, then row softmax ----
  for (int i = t; i < 2401; i += T) {
    int cA = i / 49, c2 = i - cA * 49;
    sW[c2 * 72 + cA] = (_Float16)P.alw[i];        // alwT [49->64][72]
  }
  for (int i = t; i < 735; i += T) {              // zero alwT k-pad (c 49..63), rows c2<49
    int c2 = i / 15, cA = 49 + (i - (i / 15) * 15);
    sW[c2 * 72 + cA] = (_Float16)0.f;
  }
  __syncthreads();
  _Float16* A1 = (_Float16*)sKQ;                  // reuse Kn/Qn: [3][64][72]
  #pragma unroll
  for (int i = 0; i < 3; i++) {
    int tt = wid + 16 * i;
    int h = tt >> 4, r16 = tt & 15, tmf = r16 >> 2, tnc = r16 & 3;
    f32x4 c = {0.f, 0.f, 0.f, 0.f};
    #pragma unroll
    for (int ks = 0; ks < 2; ks++) {
      f16x8 a  = *(const f16x8*)&sA0[h * 4608 + (tmf * 16 + lr) * 72 + ks * 32 + lk * 8];
      f16x8 bf = *(const f16x8*)&sW[(tnc * 16 + lr) * 72 + ks * 32 + lk * 8];
      c = MFMA16(a, bf, c);
    }
    int c2 = tnc * 16 + lr;
    if (c2 < 49) {
      float ab = P.alb[c2];
      #pragma unroll
      for (int r = 0; r < 4; r++) {
        int f = tmf * 16 + lk * 4 + r;
        if (f < 49) A1[h * 4608 + f * 72 + c2] = (_Float16)(c[r] + ab);
      }
    }
  }
  for (int i = t; i < 2205; i += T) {             // zero A1 k-pad cols
    int h = i / 735, r2 = i - h * 735, f = r2 / 15, cc = 49 + (r2 - (r2 / 15) * 15);
    A1[h * 4608 + f * 72 + cc] = (_Float16)0.f;
  }
  __syncthreads();
  for (int r = t; r < 147; r += T) {              // row softmax (147 rows x 49)
    _Float16* row = A1 + (r / 49) * 4608 + (r - (r / 49) * 49) * 72;
    float m = -1e30f;
    for (int c = 0; c < 49; c++) m = fmaxf(m, (float)row[c]);
    float s = 0.f;
    for (int c = 0; c < 49; c++) s += __expf((float)row[c] - m);
    float inv = 1.f / s;
    for (int c = 0; c < 49; c++) row[c] = (_Float16)(__expf((float)row[c] - m) * inv);
  }
  __syncthreads();

  // ---- P4 (S6): E = softmax(A1) @ V  (B-op = V^T, ready) -> E [49][200] in sA0 ----
  #pragma unroll
  for (int i = 0; i < 3; i++) {
    int tt = wid + 16 * i;
    int h = tt >> 4, r16 = tt & 15, tmf = r16 >> 2, tnd = r16 & 3;
    f32x4 c = {0.f, 0.f, 0.f, 0.f};
    #pragma unroll
    for (int ks = 0; ks < 2; ks++) {
      f16x8 a  = *(const f16x8*)&A1[h * 4608 + (tmf * 16 + lr) * 72 + ks * 32 + lk * 8];
      f16x8 bv = *(const f16x8*)&sVT[(h * 64 + tnd * 16 + lr) * 72 + ks * 32 + lk * 8];
      c = MFMA16(a, bv, c);
    }
    int d = tnd * 16 + lr;
    #pragma unroll
    for (int r = 0; r < 4; r++) {
      int f = tmf * 16 + lk * 4 + r;
      if (f < 49) sA0[f * 200 + h * 64 + d] = (_Float16)c[r];   // E (A0 dead)
    }
  }
  __syncthreads();

  // ---- P5 (S7): F = relu(E @ l1w + l1b) -> LN -> colmax -> lin2 -> elu ----
  for (int i = t; i < 12288; i += T) {
    int k = i >> 6, n = i & 63;
    sW[n * 200 + k] = (_Float16)P.l1w[i];          // l1wT [64][200], k=192 exact
  }
  __syncthreads();
  {
    int tmf = wid >> 2, tnn = wid & 3;             // 16 tiles, 1 per wave
    f32x4 c = {0.f, 0.f, 0.f, 0.f};
    #pragma unroll
    for (int ks = 0; ks < 6; ks++) {
      f16x8 a  = *(const f16x8*)&sA0[(tmf * 16 + lr) * 200 + ks * 32 + lk * 8];
      f16x8 bf = *(const f16x8*)&sW[(tnn * 16 + lr) * 200 + ks * 32 + lk * 8];
      c = MFMA16(a, bf, c);
    }
    float* F = (float*)sVT;                        // [49][68] fp32 (VT dead)
    int n = tnn * 16 + lr;
    float bn = P.l1b[n];
    float s8 = 0.f, q8 = 0.f;
    #pragma unroll
    for (int r = 0; r < 4; r++) {
      int f = tmf * 16 + lk * 4 + r;
      if (f < 49) {
        float v = fmaxf(c[r] + bn, 0.f);
        F[f * 68 + n] = v;
        s8 += v; q8 += v * v;
      }
    }
    block_reduce2(s8, q8, sRed, t);                // first barrier fences F writes
    float m8 = s8 * (1.f / 3136.f);
    float r8 = rsqrtf(q8 * (1.f / 3136.f) - m8 * m8 + EPS);
    if (t < 64) {
      float mx = -1e30f;
      for (int f = 0; f < 49; f++) mx = fmaxf(mx, F[f * 68 + t]);
      sM[t] = (mx - m8) * r8;                      // rstd > 0: max commutes with normalize
    }
    __syncthreads();
    if (t < 5) {
      float a2 = P.l2b[t];
      #pragma unroll 16
      for (int d = 0; d < 64; d++) a2 += sM[d] * P.l2w[d * 5 + t];
      P.out[b * 5 + t] = elu_f(a2);
    }
  }
}

extern "C" void kernel_launch(void* const* d_in, const int* in_sizes, int n_in,
                              void* d_out, int out_size, void* d_ws, size_t ws_size,
                              hipStream_t stream) {
  Params P;
  P.x   = (const float*)d_in[0];
  P.c1w = (const float*)d_in[1];  P.c1b = (const float*)d_in[2];
  P.c2w = (const float*)d_in[3];  P.c2b = (const float*)d_in[4];
  P.kpw = (const float*)d_in[5];  P.kpb = (const float*)d_in[6];
  P.qpw = (const float*)d_in[7];  P.qpb = (const float*)d_in[8];
  P.vpw = (const float*)d_in[9];  P.vpb = (const float*)d_in[10];
  P.kng = (const float*)d_in[11]; P.knb = (const float*)d_in[12];
  P.qng = (const float*)d_in[13]; P.qnb = (const float*)d_in[14];
  P.vng = (const float*)d_in[15]; P.vnb = (const float*)d_in[16];
  P.klw = (const float*)d_in[17]; P.klb = (const float*)d_in[18];
  P.qlw = (const float*)d_in[19]; P.qlb = (const float*)d_in[20];
  P.alw = (const float*)d_in[21]; P.alb = (const float*)d_in[22];
  P.l1w = (const float*)d_in[23]; P.l1b = (const float*)d_in[24];
  P.l2w = (const float*)d_in[25]; P.l2b = (const float*)d_in[26];
  P.out = (float*)d_out;

  int B = in_sizes[0] / 147;   // [B,3,7,7]
  hipLaunchKernelGGL(mhr_fused, dim3(B), dim3(T), 0, stream, P);
}

// Round 5
// 713.089 us; speedup vs baseline: 3.1587x; 1.4222x over previous
//
#include <hip/hip_runtime.h>

#define T 1024
#define EPS 1e-5f

typedef _Float16 f16x8 __attribute__((ext_vector_type(8)));
typedef float f32x4 __attribute__((ext_vector_type(4)));

#define MFMA16(a, b, c) __builtin_amdgcn_mfma_f32_16x16x32_f16((a), (b), (c), 0, 0, 0)

struct Params {
  const float *x;
  const float *c1w, *c1b, *c2w, *c2b;
  const float *kpw, *kpb, *qpw, *qpb, *vpw, *vpb;
  const float *kng, *knb, *qng, *qnb, *vng, *vnb;
  const float *klw, *klb, *qlw, *qlb, *alw, *alb;
  const float *l1w, *l1b, *l2w, *l2b;
  float *out;
};

// ws layout (f16 elements):
//   0     : kpwT [192][32]  (K-pad c 22..31 zeroed)
//   6144  : qpwT [192][32]
//   12288 : vpwT [192][32]
//   18432 : qlwT [64][64]   (rows c>=49 zeroed)
//   22528 : klwT [64][64]
//   26624 : alwT [64][64]   (rows c2>=49 AND k-cols cA>=49 zeroed)
//   30720 : l1wT [64][192]
// total 43008 f16 = 86016 B
__global__ __launch_bounds__(256) void prep_weights(Params P, _Float16* ws) {
  int t0 = blockIdx.x * 256 + threadIdx.x;
  int stride = gridDim.x * 256;
  for (int i = t0; i < 3 * 6144; i += stride) {
    int pr = i / 6144, r = i - pr * 6144;
    int j = r >> 5, c = r & 31;
    const float* w = pr == 0 ? P.kpw : pr == 1 ? P.qpw : P.vpw;
    ws[i] = (c < 22) ? (_Float16)w[c * 192 + j] : (_Float16)0.f;
  }
  for (int i = t0; i < 2 * 4096; i += stride) {
    int pr = i >> 12, r = i & 4095;
    int c = r >> 6, d = r & 63;
    const float* w = pr == 0 ? P.qlw : P.klw;
    ws[18432 + i] = (c < 49) ? (_Float16)w[d * 49 + c] : (_Float16)0.f;
  }
  for (int i = t0; i < 4096; i += stride) {
    int c2 = i >> 6, cA = i & 63;
    ws[26624 + i] = (c2 < 49 && cA < 49) ? (_Float16)P.alw[cA * 49 + c2] : (_Float16)0.f;
  }
  for (int i = t0; i < 12288; i += stride) {
    int n = i / 192, k = i - n * 192;
    ws[30720 + i] = (_Float16)P.l1w[k * 64 + n];
  }
}

__device__ inline float elu_f(float v) { return v > 0.f ? v : __expf(v) - 1.f; }

__device__ inline void block_reduce6(float* v, float* sRed, int t) {
  int lane = t & 63, wid = t >> 6;
  #pragma unroll
  for (int k = 0; k < 6; k++) {
    float x = v[k];
    #pragma unroll
    for (int off = 32; off; off >>= 1) x += __shfl_down(x, off, 64);
    if (lane == 0) sRed[k * 16 + wid] = x;
  }
  __syncthreads();
  if (t < 6) {
    float s = 0.f;
    #pragma unroll
    for (int w = 0; w < 16; w++) s += sRed[t * 16 + w];
    sRed[t * 16] = s;
  }
  __syncthreads();
  #pragma unroll
  for (int k = 0; k < 6; k++) v[k] = sRed[k * 16];
}

__device__ inline void block_reduce2(float& sum, float& sq, float* sRed, int t) {
  int lane = t & 63, wid = t >> 6;
  #pragma unroll
  for (int off = 32; off; off >>= 1) {
    sum += __shfl_down(sum, off, 64);
    sq  += __shfl_down(sq,  off, 64);
  }
  if (lane == 0) { sRed[wid] = sum; sRed[16 + wid] = sq; }
  __syncthreads();
  if (t == 0) {
    float s = 0.f, q = 0.f;
    #pragma unroll
    for (int w = 0; w < 16; w++) { s += sRed[w]; q += sRed[16 + w]; }
    sRed[0] = s; sRed[16] = q;
  }
  __syncthreads();
  sum = sRed[0]; sq = sRed[16];
}

// MFMA fragment conventions (16x16x32, fp16 in / fp32 out):
//   A-frag: lane l holds A[row = l&15][k = (l>>4)*8 + e]           ([M][K] row-major)
//   B-frag: lane l holds B[k = (l>>4)*8 + e][col = l&15]           (from BT[N][K] row-major)
//   C/D  : lane l, reg r -> D[row = (l>>4)*4 + r][col = l&15]
// LDS f16 strides 40/72/200 give conflict-free ds_read_b128.

__global__ __launch_bounds__(T) void mhr_fused(Params P, const _Float16* __restrict__ ws) {
  const int b = blockIdx.x;
  const int t = threadIdx.x;
  const int wid = t >> 6, l = t & 63, lr = l & 15, lk = l >> 4;

  __shared__ __align__(16) _Float16 sKQ[2][9800];  // Kn/Qn [49][200]; later A1 [3][64][72]
  __shared__ __align__(16) _Float16 sVT[13824];    // P0 scratch; V^T [192][72]; later F fp32 [49][68]
  __shared__ __align__(16) _Float16 sA0[13824];    // A0 [3][64][72]; later E [49][200]
  __shared__ __align__(16) _Float16 sTok[2560];    // tokens A-tile [64][40]
  __shared__ float sRed[96];
  __shared__ float sM[64];

  // ---- pre-zero sTok (full) and sA0 (full: provides all K-pad zeros) ----
  for (int i = t; i < 1280; i += T) ((unsigned*)sTok)[i] = 0u;
  for (int i = t; i < 6912; i += T) ((unsigned*)sA0)[i] = 0u;

  // ---- P0: x -> tokens as fp16 A-tile [64][40] ----
  float* xb = (float*)sVT;        // 147 floats (scratch, dead before V^T written)
  float* h1 = (float*)sVT + 160;  // 784 floats
  for (int i = t; i < 147; i += T) xb[i] = P.x[b * 147 + i];
  __syncthreads();
  for (int i = t; i < 784; i += T) {
    int p = i >> 4, o = i & 15;
    float a = P.c1b[o] + xb[p] * P.c1w[o * 3] + xb[49 + p] * P.c1w[o * 3 + 1]
            + xb[98 + p] * P.c1w[o * 3 + 2];
    h1[p * 16 + o] = fmaxf(a, 0.f);
  }
  __syncthreads();
  for (int i = t; i < 980; i += T) {
    int p = i / 20, o = i - p * 20;
    float a = P.c2b[o];
    #pragma unroll
    for (int c = 0; c < 16; c++) a += h1[p * 16 + c] * P.c2w[o * 16 + c];
    sTok[p * 40 + o] = (_Float16)fmaxf(a, 0.f);
  }
  for (int i = t; i < 49; i += T) {
    sTok[i * 40 + 20] = (_Float16)((float)(i % 7) * (1.f / 7.f));
    sTok[i * 40 + 21] = (_Float16)((float)(i / 7) * (1.f / 7.f));
  }
  __syncthreads();

  // ---- P1: K/Q/V projections (merged, B/A weight frags direct from ws) + LN ----
  f32x4 cK[3], cQ[3], cV[3];
  float st[6] = {0.f, 0.f, 0.f, 0.f, 0.f, 0.f};
  #pragma unroll
  for (int i = 0; i < 3; i++) {
    int tt = wid + 16 * i;
    int tm = tt / 12, tn = tt - tm * 12;          // K/Q: D[p][j], 4x12 tiles
    f16x8 a  = *(const f16x8*)&sTok[(tm * 16 + lr) * 40 + lk * 8];
    f16x8 bK = *(const f16x8*)&ws[(tn * 16 + lr) * 32 + lk * 8];
    f16x8 bQ = *(const f16x8*)&ws[6144 + (tn * 16 + lr) * 32 + lk * 8];
    f32x4 z = {0.f, 0.f, 0.f, 0.f};
    f32x4 k4 = MFMA16(a, bK, z);
    f32x4 q4 = MFMA16(a, bQ, z);
    float bjK = P.kpb[tn * 16 + lr];
    float bjQ = P.qpb[tn * 16 + lr];
    #pragma unroll
    for (int r = 0; r < 4; r++) {
      int p = tm * 16 + lk * 4 + r;
      float vk = k4[r] + bjK, vq = q4[r] + bjQ;
      k4[r] = vk; q4[r] = vq;
      if (p < 49) { st[0] += vk; st[1] += vk * vk; st[2] += vq; st[3] += vq * vq; }
    }
    cK[i] = k4; cQ[i] = q4;
    int vm = tt >> 2, vn = tt & 3;                // V^T: D[j][p], 12x4 tiles, swapped ops
    f16x8 av = *(const f16x8*)&ws[12288 + (vm * 16 + lr) * 32 + lk * 8];
    f16x8 bt = *(const f16x8*)&sTok[(vn * 16 + lr) * 40 + lk * 8];
    f32x4 v4 = MFMA16(av, bt, z);
    int pv = vn * 16 + lr;
    #pragma unroll
    for (int r = 0; r < 4; r++) {
      float vv = v4[r] + P.vpb[vm * 16 + lk * 4 + r];
      v4[r] = vv;
      if (pv < 49) { st[4] += vv; st[5] += vv * vv; }
    }
    cV[i] = v4;
  }
  block_reduce6(st, sRed, t);
  float muK = st[0] * (1.f / 9408.f), rrK = rsqrtf(st[1] * (1.f / 9408.f) - muK * muK + EPS);
  float muQ = st[2] * (1.f / 9408.f), rrQ = rsqrtf(st[3] * (1.f / 9408.f) - muQ * muQ + EPS);
  float muV = st[4] * (1.f / 9408.f), rrV = rsqrtf(st[5] * (1.f / 9408.f) - muV * muV + EPS);
  #pragma unroll
  for (int i = 0; i < 3; i++) {
    int tt = wid + 16 * i;
    int tm = tt / 12, tn = tt - tm * 12;
    int j = tn * 16 + lr, h = j >> 6, d = j & 63;
    #pragma unroll
    for (int r = 0; r < 4; r++) {
      int p = tm * 16 + lk * 4 + r;
      if (p < 49) {
        int gi = (h * 49 + p) * 64 + d;
        sKQ[0][p * 200 + j] = (_Float16)((cK[i][r] - muK) * rrK * P.kng[gi] + P.knb[gi]);
        sKQ[1][p * 200 + j] = (_Float16)((cQ[i][r] - muQ) * rrQ * P.qng[gi] + P.qnb[gi]);
      }
    }
    int vm = tt >> 2, vn = tt & 3;
    int pv = vn * 16 + lr;
    if (pv < 49) {
      #pragma unroll
      for (int r = 0; r < 4; r++) {
        int j2 = vm * 16 + lk * 4 + r;
        int gi = ((j2 >> 6) * 49 + pv) * 64 + (j2 & 63);
        sVT[j2 * 72 + pv] = (_Float16)((cV[i][r] - muV) * rrV * P.vng[gi] + P.vnb[gi]);
      }
    }
  }
  for (int i = t; i < 2880; i += T) {             // zero V^T K-pad cols p 49..63
    int j = i / 15, p = 49 + (i - (i / 15) * 15);
    sVT[j * 72 + p] = (_Float16)0.f;
  }
  __syncthreads();

  // ---- P2: A0 = elu(Qn@qlw + Kn@klw + bias) ----
  #pragma unroll
  for (int i = 0; i < 3; i++) {
    int tt = wid + 16 * i;
    int h = tt >> 4, r16 = tt & 15, tmf = r16 >> 2, tnc = r16 & 3;
    f32x4 c = {0.f, 0.f, 0.f, 0.f};
    #pragma unroll
    for (int ks = 0; ks < 2; ks++) {
      f16x8 aQ = *(const f16x8*)&sKQ[1][(tmf * 16 + lr) * 200 + h * 64 + ks * 32 + lk * 8];
      f16x8 bQ = *(const f16x8*)&ws[18432 + (tnc * 16 + lr) * 64 + ks * 32 + lk * 8];
      c = MFMA16(aQ, bQ, c);
      f16x8 aK = *(const f16x8*)&sKQ[0][(tmf * 16 + lr) * 200 + h * 64 + ks * 32 + lk * 8];
      f16x8 bK = *(const f16x8*)&ws[22528 + (tnc * 16 + lr) * 64 + ks * 32 + lk * 8];
      c = MFMA16(aK, bK, c);
    }
    int cc = tnc * 16 + lr;
    if (cc < 49) {
      float cb = P.qlb[cc] + P.klb[cc];
      #pragma unroll
      for (int r = 0; r < 4; r++) {
        int f = tmf * 16 + lk * 4 + r;
        if (f < 49) sA0[h * 4608 + f * 72 + cc] = (_Float16)elu_f(c[r] + cb);
      }
    }
  }
  __syncthreads();

  // ---- P3: A1 = A0 @ alw + alb (into sKQ region) ----
  _Float16* A1 = (_Float16*)sKQ;                  // [3][64][72]
  #pragma unroll
  for (int i = 0; i < 3; i++) {
    int tt = wid + 16 * i;
    int h = tt >> 4, r16 = tt & 15, tmf = r16 >> 2, tnc = r16 & 3;
    f32x4 c = {0.f, 0.f, 0.f, 0.f};
    #pragma unroll
    for (int ks = 0; ks < 2; ks++) {
      f16x8 a  = *(const f16x8*)&sA0[h * 4608 + (tmf * 16 + lr) * 72 + ks * 32 + lk * 8];
      f16x8 bf = *(const f16x8*)&ws[26624 + (tnc * 16 + lr) * 64 + ks * 32 + lk * 8];
      c = MFMA16(a, bf, c);
    }
    int c2 = tnc * 16 + lr;
    if (c2 < 49) {
      float ab = P.alb[c2];
      #pragma unroll
      for (int r = 0; r < 4; r++) {
        int f = tmf * 16 + lk * 4 + r;
        if (f < 49) A1[h * 4608 + f * 72 + c2] = (_Float16)(c[r] + ab);
      }
    }
  }
  __syncthreads();

  // ---- softmax: 8 lanes per row, 147 rows; also writes K-pad zeros c 49..63 ----
  for (int task = t; task < 1176; task += T) {
    int r = task >> 3, cg = l & 7;
    _Float16* row = A1 + (r / 49) * 4608 + (r - (r / 49) * 49) * 72;
    float vals[8];
    float mx = -1e30f;
    #pragma unroll
    for (int u = 0; u < 8; u++) {
      int c = cg + u * 8;
      float v = (c < 49) ? (float)row[c] : -1e30f;
      vals[u] = v;
      mx = fmaxf(mx, v);
    }
    mx = fmaxf(mx, __shfl_xor(mx, 1, 64));
    mx = fmaxf(mx, __shfl_xor(mx, 2, 64));
    mx = fmaxf(mx, __shfl_xor(mx, 4, 64));
    float s = 0.f;
    #pragma unroll
    for (int u = 0; u < 8; u++) {
      int c = cg + u * 8;
      float e = (c < 49) ? __expf(vals[u] - mx) : 0.f;
      vals[u] = e;
      s += e;
    }
    s += __shfl_xor(s, 1, 64);
    s += __shfl_xor(s, 2, 64);
    s += __shfl_xor(s, 4, 64);
    float inv = 1.f / s;
    #pragma unroll
    for (int u = 0; u < 8; u++) {
      int c = cg + u * 8;
      row[c] = (_Float16)(vals[u] * inv);
    }
  }
  __syncthreads();

  // ---- P4: E = softmax(A1) @ V  (B-op = V^T) -> E [49][200] in sA0 ----
  #pragma unroll
  for (int i = 0; i < 3; i++) {
    int tt = wid + 16 * i;
    int h = tt >> 4, r16 = tt & 15, tmf = r16 >> 2, tnd = r16 & 3;
    f32x4 c = {0.f, 0.f, 0.f, 0.f};
    #pragma unroll
    for (int ks = 0; ks < 2; ks++) {
      f16x8 a  = *(const f16x8*)&A1[h * 4608 + (tmf * 16 + lr) * 72 + ks * 32 + lk * 8];
      f16x8 bv = *(const f16x8*)&sVT[(h * 64 + tnd * 16 + lr) * 72 + ks * 32 + lk * 8];
      c = MFMA16(a, bv, c);
    }
    int d = tnd * 16 + lr;
    #pragma unroll
    for (int r = 0; r < 4; r++) {
      int f = tmf * 16 + lk * 4 + r;
      if (f < 49) sA0[f * 200 + h * 64 + d] = (_Float16)c[r];
    }
  }
  __syncthreads();

  // ---- P5: F = relu(E @ l1w + l1b) -> LN -> colmax -> lin2 -> elu ----
  {
    int tmf = wid >> 2, tnn = wid & 3;            // 16 tiles, 1 per wave
    f32x4 c = {0.f, 0.f, 0.f, 0.f};
    #pragma unroll
    for (int ks = 0; ks < 6; ks++) {
      f16x8 a  = *(const f16x8*)&sA0[(tmf * 16 + lr) * 200 + ks * 32 + lk * 8];
      f16x8 bf = *(const f16x8*)&ws[30720 + (tnn * 16 + lr) * 192 + ks * 32 + lk * 8];
      c = MFMA16(a, bf, c);
    }
    float* F = (float*)sVT;                       // [49][68] fp32 (V^T dead)
    int n = tnn * 16 + lr;
    float bn = P.l1b[n];
    float s8 = 0.f, q8 = 0.f;
    #pragma unroll
    for (int r = 0; r < 4; r++) {
      int f = tmf * 16 + lk * 4 + r;
      if (f < 49) {
        float v = fmaxf(c[r] + bn, 0.f);
        F[f * 68 + n] = v;
        s8 += v; q8 += v * v;
      }
    }
    block_reduce2(s8, q8, sRed, t);               // first barrier fences F writes
    float m8 = s8 * (1.f / 3136.f);
    float r8 = rsqrtf(q8 * (1.f / 3136.f) - m8 * m8 + EPS);
    if (t < 64) {
      float mx = -1e30f;
      for (int f = 0; f < 49; f++) mx = fmaxf(mx, F[f * 68 + t]);
      sM[t] = (mx - m8) * r8;                     // rstd > 0: max commutes with normalize
    }
    __syncthreads();
    if (t < 5) {
      float a2 = P.l2b[t];
      #pragma unroll 16
      for (int d = 0; d < 64; d++) a2 += sM[d] * P.l2w[d * 5 + t];
      P.out[b * 5 + t] = elu_f(a2);
    }
  }
}

extern "C" void kernel_launch(void* const* d_in, const int* in_sizes, int n_in,
                              void* d_out, int out_size, void* d_ws, size_t ws_size,
                              hipStream_t stream) {
  Params P;
  P.x   = (const float*)d_in[0];
  P.c1w = (const float*)d_in[1];  P.c1b = (const float*)d_in[2];
  P.c2w = (const float*)d_in[3];  P.c2b = (const float*)d_in[4];
  P.kpw = (const float*)d_in[5];  P.kpb = (const float*)d_in[6];
  P.qpw = (const float*)d_in[7];  P.qpb = (const float*)d_in[8];
  P.vpw = (const float*)d_in[9];  P.vpb = (const float*)d_in[10];
  P.kng = (const float*)d_in[11]; P.knb = (const float*)d_in[12];
  P.qng = (const float*)d_in[13]; P.qnb = (const float*)d_in[14];
  P.vng = (const float*)d_in[15]; P.vnb = (const float*)d_in[16];
  P.klw = (const float*)d_in[17]; P.klb = (const float*)d_in[18];
  P.qlw = (const float*)d_in[19]; P.qlb = (const float*)d_in[20];
  P.alw = (const float*)d_in[21]; P.alb = (const float*)d_in[22];
  P.l1w = (const float*)d_in[23]; P.l1b = (const float*)d_in[24];
  P.l2w = (const float*)d_in[25]; P.l2b = (const float*)d_in[26];
  P.out = (float*)d_out;

  _Float16* ws = (_Float16*)d_ws;   // 86016 B used
  hipLaunchKernelGGL(prep_weights, dim3(64), dim3(256), 0, stream, P, ws);

  int B = in_sizes[0] / 147;   // [B,3,7,7]
  hipLaunchKernelGGL(mhr_fused, dim3(B), dim3(T), 0, stream, P, ws);
}

// Round 6
// 590.813 us; speedup vs baseline: 3.8124x; 1.2070x over previous
//
#include <hip/hip_runtime.h>

#define T 1024
#define EPS 1e-5f

typedef _Float16 f16x8 __attribute__((ext_vector_type(8)));
typedef _Float16 f16x4 __attribute__((ext_vector_type(4)));
typedef _Float16 f16x2 __attribute__((ext_vector_type(2)));
typedef float f32x4 __attribute__((ext_vector_type(4)));

#define MFMA16(a, b, c) __builtin_amdgcn_mfma_f32_16x16x32_f16((a), (b), (c), 0, 0, 0)

struct Params {
  const float *x;
  const float *c1w, *c1b, *c2w, *c2b;
  const float *kpw, *kpb, *qpw, *qpb, *vpw, *vpb;
  const float *kng, *knb, *qng, *qnb, *vng, *vnb;
  const float *klw, *klb, *qlw, *qlb, *alw, *alb;
  const float *l1w, *l1b, *l2w, *l2b;
  float *out;
};

// ws layout (f16 units):
//   0      kpwT [192][32]   (K-pad c 22..31 zeroed)
//   6144   qpwT [192][32]
//   12288  vpwT [192][32]
//   18432  qlwT [64][64]    (rows c>=49 zeroed)
//   22528  klwT [64][64]
//   26624  alwT [64][64]    (rows c2>=49 AND k-cols cA>=49 zeroed)
//   30720  l1wT [64][192]
//   43008  gbKQ [9408][4]   (kng,knb,qng,qnb) f16x4
//   80640  gbV  [9408][2]   (vng,vnb) f16x2
//   99456  bKQ  [192][2]    (kpb,qpb) f16x2
//   99840  vpb  [192]
//   100032 cbb  [64]        (qlb+klb, 0 for c>=49)
//   100096 alb  [64]        (0 for c>=49)
//   100160 l1b  [64]
// total 100224 f16 = 200448 B
__global__ __launch_bounds__(256) void prep_weights(Params P, _Float16* ws) {
  int t0 = blockIdx.x * 256 + threadIdx.x;
  int stride = gridDim.x * 256;
  for (int i = t0; i < 3 * 6144; i += stride) {
    int pr = i / 6144, r = i - pr * 6144;
    int j = r >> 5, c = r & 31;
    const float* w = pr == 0 ? P.kpw : pr == 1 ? P.qpw : P.vpw;
    ws[i] = (c < 22) ? (_Float16)w[c * 192 + j] : (_Float16)0.f;
  }
  for (int i = t0; i < 2 * 4096; i += stride) {
    int pr = i >> 12, r = i & 4095;
    int c = r >> 6, d = r & 63;
    const float* w = pr == 0 ? P.qlw : P.klw;
    ws[18432 + i] = (c < 49) ? (_Float16)w[d * 49 + c] : (_Float16)0.f;
  }
  for (int i = t0; i < 4096; i += stride) {
    int c2 = i >> 6, cA = i & 63;
    ws[26624 + i] = (c2 < 49 && cA < 49) ? (_Float16)P.alw[cA * 49 + c2] : (_Float16)0.f;
  }
  for (int i = t0; i < 12288; i += stride) {
    int n = i / 192, k = i - n * 192;
    ws[30720 + i] = (_Float16)P.l1w[k * 64 + n];
  }
  for (int i = t0; i < 9408; i += stride) {
    f16x4 v = {(_Float16)P.kng[i], (_Float16)P.knb[i], (_Float16)P.qng[i], (_Float16)P.qnb[i]};
    *(f16x4*)&ws[43008 + i * 4] = v;
    f16x2 v2 = {(_Float16)P.vng[i], (_Float16)P.vnb[i]};
    *(f16x2*)&ws[80640 + i * 2] = v2;
  }
  for (int i = t0; i < 192; i += stride) {
    f16x2 v = {(_Float16)P.kpb[i], (_Float16)P.qpb[i]};
    *(f16x2*)&ws[99456 + i * 2] = v;
    ws[99840 + i] = (_Float16)P.vpb[i];
  }
  for (int i = t0; i < 64; i += stride) {
    ws[100032 + i] = (i < 49) ? (_Float16)(P.qlb[i] + P.klb[i]) : (_Float16)0.f;
    ws[100096 + i] = (i < 49) ? (_Float16)P.alb[i] : (_Float16)0.f;
    ws[100160 + i] = (_Float16)P.l1b[i];
  }
}

__device__ inline float elu_f(float v) { return v > 0.f ? v : __expf(v) - 1.f; }

__device__ inline void block_reduce6(float* v, float* sRed, int t) {
  int lane = t & 63, wid = t >> 6;
  #pragma unroll
  for (int k = 0; k < 6; k++) {
    float x = v[k];
    #pragma unroll
    for (int off = 32; off; off >>= 1) x += __shfl_down(x, off, 64);
    if (lane == 0) sRed[k * 16 + wid] = x;
  }
  __syncthreads();
  if (t < 6) {
    float s = 0.f;
    #pragma unroll
    for (int w = 0; w < 16; w++) s += sRed[t * 16 + w];
    sRed[t * 16] = s;
  }
  __syncthreads();
  #pragma unroll
  for (int k = 0; k < 6; k++) v[k] = sRed[k * 16];
}

__device__ inline void block_reduce2(float& sum, float& sq, float* sRed, int t) {
  int lane = t & 63, wid = t >> 6;
  #pragma unroll
  for (int off = 32; off; off >>= 1) {
    sum += __shfl_down(sum, off, 64);
    sq  += __shfl_down(sq,  off, 64);
  }
  if (lane == 0) { sRed[wid] = sum; sRed[16 + wid] = sq; }
  __syncthreads();
  if (t == 0) {
    float s = 0.f, q = 0.f;
    #pragma unroll
    for (int w = 0; w < 16; w++) { s += sRed[w]; q += sRed[16 + w]; }
    sRed[0] = s; sRed[16] = q;
  }
  __syncthreads();
  sum = sRed[0]; sq = sRed[16];
}

// MFMA fragment conventions (16x16x32, fp16 in / fp32 out):
//   A-frag: lane l holds A[row = l&15][k = (l>>4)*8 + e]           ([M][K] row-major)
//   B-frag: lane l holds B[k = (l>>4)*8 + e][col = l&15]           (from BT[N][K] row-major)
//   C/D  : lane l, reg r -> D[row = (l>>4)*4 + r][col = l&15]
// LDS f16 strides 40/72/200 give conflict-free (<=2-way) ds_read_b128.

__global__ __launch_bounds__(T) void mhr_fused(Params P, const _Float16* __restrict__ ws) {
  const int b = blockIdx.x;
  const int t = threadIdx.x;
  const int wid = t >> 6, l = t & 63, lr = l & 15, lk = l >> 4;

  __shared__ __align__(16) _Float16 sKQ[2][9800];  // Kn/Qn [49][200]; later A1 [3][64][72]
  __shared__ __align__(16) _Float16 sVT[13824];    // P0 scratch; V^T [192][72]; later F fp32 [49][68]
  __shared__ __align__(16) _Float16 sA0[13824];    // A0 [3][64][72]; later E [49][200]; tail scratch
  __shared__ __align__(16) _Float16 sTok[2560];    // tokens A-tile [64][40]
  __shared__ float sRed[96];
  __shared__ float sM[64];

  // ---- prefetch P1 weight frags + packed biases (consumed after P0) ----
  f16x8 wKf[3], wQf[3], wVf[3];
  f16x2 bkq[3];
  f16x4 bv[3];
  #pragma unroll
  for (int i = 0; i < 3; i++) {
    int tt = wid + 16 * i;
    int tm = tt / 12, tn = tt - tm * 12;
    (void)tm;
    int vm = tt >> 2;
    wKf[i] = *(const f16x8*)&ws[(tn * 16 + lr) * 32 + lk * 8];
    wQf[i] = *(const f16x8*)&ws[6144 + (tn * 16 + lr) * 32 + lk * 8];
    wVf[i] = *(const f16x8*)&ws[12288 + (vm * 16 + lr) * 32 + lk * 8];
    bkq[i] = *(const f16x2*)&ws[99456 + (tn * 16 + lr) * 2];
    bv[i]  = *(const f16x4*)&ws[99840 + vm * 16 + lk * 4];
  }

  // ---- pre-zero sTok (full) + sA0 K-pad cols (c 49..63, valid rows) ----
  for (int i = t; i < 1280; i += T) ((unsigned*)sTok)[i] = 0u;
  for (int i = t; i < 2205; i += T) {
    int h = i / 735, r2 = i - h * 735, f = r2 / 15, cc = 49 + (r2 - f * 15);
    sA0[h * 4608 + f * 72 + cc] = (_Float16)0.f;
  }

  // ---- P0: x -> tokens as fp16 A-tile [64][40] ----
  float* xb = (float*)sVT;        // 147 floats (scratch, dead before V^T written)
  float* h1 = (float*)sVT + 160;  // 784 floats
  for (int i = t; i < 147; i += T) xb[i] = P.x[b * 147 + i];
  __syncthreads();
  for (int i = t; i < 784; i += T) {
    int p = i >> 4, o = i & 15;
    float a = P.c1b[o] + xb[p] * P.c1w[o * 3] + xb[49 + p] * P.c1w[o * 3 + 1]
            + xb[98 + p] * P.c1w[o * 3 + 2];
    h1[p * 16 + o] = fmaxf(a, 0.f);
  }
  __syncthreads();
  for (int i = t; i < 980; i += T) {
    int p = i / 20, o = i - p * 20;
    float a = P.c2b[o];
    #pragma unroll
    for (int c = 0; c < 16; c++) a += h1[p * 16 + c] * P.c2w[o * 16 + c];
    sTok[p * 40 + o] = (_Float16)fmaxf(a, 0.f);
  }
  for (int i = t; i < 49; i += T) {
    sTok[i * 40 + 20] = (_Float16)((float)(i % 7) * (1.f / 7.f));
    sTok[i * 40 + 21] = (_Float16)((float)(i / 7) * (1.f / 7.f));
  }
  __syncthreads();

  // ---- P1: K/Q/V projections (merged) + LN ----
  f32x4 cK[3], cQ[3], cV[3];
  float st[6] = {0.f, 0.f, 0.f, 0.f, 0.f, 0.f};
  #pragma unroll
  for (int i = 0; i < 3; i++) {
    int tt = wid + 16 * i;
    int tm = tt / 12;
    f16x8 a  = *(const f16x8*)&sTok[(tm * 16 + lr) * 40 + lk * 8];
    f32x4 z = {0.f, 0.f, 0.f, 0.f};
    f32x4 k4 = MFMA16(a, wKf[i], z);
    f32x4 q4 = MFMA16(a, wQf[i], z);
    float bjK = (float)bkq[i].x;
    float bjQ = (float)bkq[i].y;
    #pragma unroll
    for (int r = 0; r < 4; r++) {
      int p = tm * 16 + lk * 4 + r;
      float vk = k4[r] + bjK, vq = q4[r] + bjQ;
      k4[r] = vk; q4[r] = vq;
      if (p < 49) { st[0] += vk; st[1] += vk * vk; st[2] += vq; st[3] += vq * vq; }
    }
    cK[i] = k4; cQ[i] = q4;
    int vn = tt & 3;
    f16x8 bt = *(const f16x8*)&sTok[(vn * 16 + lr) * 40 + lk * 8];
    f32x4 v4 = MFMA16(wVf[i], bt, z);
    int pv = vn * 16 + lr;
    #pragma unroll
    for (int r = 0; r < 4; r++) {
      float vv = v4[r] + (float)bv[i][r];
      v4[r] = vv;
      if (pv < 49) { st[4] += vv; st[5] += vv * vv; }
    }
    cV[i] = v4;
  }
  // prefetch gamma/beta packs (covered by block_reduce6's two barriers)
  f16x4 gkq[3][4];
  f16x2 gv[3][4];
  #pragma unroll
  for (int i = 0; i < 3; i++) {
    int tt = wid + 16 * i;
    int tm = tt / 12, tn = tt - tm * 12;
    int j = tn * 16 + lr, h = j >> 6, d = j & 63;
    int vm = tt >> 2, vn = tt & 3;
    int pvc = vn * 16 + lr; if (pvc > 48) pvc = 48;
    #pragma unroll
    for (int r = 0; r < 4; r++) {
      int p = tm * 16 + lk * 4 + r; if (p > 48) p = 48;
      gkq[i][r] = *(const f16x4*)&ws[43008 + ((h * 49 + p) * 64 + d) * 4];
      int j2 = vm * 16 + lk * 4 + r;
      gv[i][r] = *(const f16x2*)&ws[80640 + (((j2 >> 6) * 49 + pvc) * 64 + (j2 & 63)) * 2];
    }
  }
  block_reduce6(st, sRed, t);
  float muK = st[0] * (1.f / 9408.f), rrK = rsqrtf(st[1] * (1.f / 9408.f) - muK * muK + EPS);
  float muQ = st[2] * (1.f / 9408.f), rrQ = rsqrtf(st[3] * (1.f / 9408.f) - muQ * muQ + EPS);
  float muV = st[4] * (1.f / 9408.f), rrV = rsqrtf(st[5] * (1.f / 9408.f) - muV * muV + EPS);
  #pragma unroll
  for (int i = 0; i < 3; i++) {
    int tt = wid + 16 * i;
    int tm = tt / 12, tn = tt - tm * 12;
    int j = tn * 16 + lr;
    #pragma unroll
    for (int r = 0; r < 4; r++) {
      int p = tm * 16 + lk * 4 + r;
      if (p < 49) {
        sKQ[0][p * 200 + j] = (_Float16)((cK[i][r] - muK) * rrK * (float)gkq[i][r].x + (float)gkq[i][r].y);
        sKQ[1][p * 200 + j] = (_Float16)((cQ[i][r] - muQ) * rrQ * (float)gkq[i][r].z + (float)gkq[i][r].w);
      }
    }
    int vm = tt >> 2, vn = tt & 3;
    int pv = vn * 16 + lr;
    #pragma unroll
    for (int r = 0; r < 4; r++) {
      int j2 = vm * 16 + lk * 4 + r;
      float nv = (pv < 49) ? ((cV[i][r] - muV) * rrV * (float)gv[i][r].x + (float)gv[i][r].y) : 0.f;
      sVT[j2 * 72 + pv] = (_Float16)nv;   // pv>=49 writes the K-pad zeros
    }
  }
  // prefetch P2 weight frags + combined bias
  f16x8 wQl[3][2], wKl[3][2];
  float cb2[3];
  #pragma unroll
  for (int i = 0; i < 3; i++) {
    int tnc = (wid + 16 * i) & 3;
    #pragma unroll
    for (int ks = 0; ks < 2; ks++) {
      wQl[i][ks] = *(const f16x8*)&ws[18432 + (tnc * 16 + lr) * 64 + ks * 32 + lk * 8];
      wKl[i][ks] = *(const f16x8*)&ws[22528 + (tnc * 16 + lr) * 64 + ks * 32 + lk * 8];
    }
    cb2[i] = (float)ws[100032 + tnc * 16 + lr];
  }
  __syncthreads();

  // ---- P2: A0 = elu(Qn@qlw + Kn@klw + bias) ----
  #pragma unroll
  for (int i = 0; i < 3; i++) {
    int tt = wid + 16 * i;
    int h = tt >> 4, r16 = tt & 15, tmf = r16 >> 2, tnc = r16 & 3;
    f32x4 c = {0.f, 0.f, 0.f, 0.f};
    #pragma unroll
    for (int ks = 0; ks < 2; ks++) {
      f16x8 aQ = *(const f16x8*)&sKQ[1][(tmf * 16 + lr) * 200 + h * 64 + ks * 32 + lk * 8];
      c = MFMA16(aQ, wQl[i][ks], c);
      f16x8 aK = *(const f16x8*)&sKQ[0][(tmf * 16 + lr) * 200 + h * 64 + ks * 32 + lk * 8];
      c = MFMA16(aK, wKl[i][ks], c);
    }
    int cc = tnc * 16 + lr;
    if (cc < 49) {
      #pragma unroll
      for (int r = 0; r < 4; r++) {
        int f = tmf * 16 + lk * 4 + r;
        if (f < 49) sA0[h * 4608 + f * 72 + cc] = (_Float16)elu_f(c[r] + cb2[i]);
      }
    }
  }
  // prefetch P3 weight frags + bias
  f16x8 wAl[3][2];
  float ab3[3];
  #pragma unroll
  for (int i = 0; i < 3; i++) {
    int tnc = (wid + 16 * i) & 3;
    #pragma unroll
    for (int ks = 0; ks < 2; ks++)
      wAl[i][ks] = *(const f16x8*)&ws[26624 + (tnc * 16 + lr) * 64 + ks * 32 + lk * 8];
    ab3[i] = (float)ws[100096 + tnc * 16 + lr];
  }
  __syncthreads();

  // ---- P3: A1 = A0 @ alw + alb (into sKQ region) ----
  _Float16* A1 = (_Float16*)sKQ;                  // [3][64][72]
  #pragma unroll
  for (int i = 0; i < 3; i++) {
    int tt = wid + 16 * i;
    int h = tt >> 4, r16 = tt & 15, tmf = r16 >> 2, tnc = r16 & 3;
    f32x4 c = {0.f, 0.f, 0.f, 0.f};
    #pragma unroll
    for (int ks = 0; ks < 2; ks++) {
      f16x8 a = *(const f16x8*)&sA0[h * 4608 + (tmf * 16 + lr) * 72 + ks * 32 + lk * 8];
      c = MFMA16(a, wAl[i][ks], c);
    }
    int c2 = tnc * 16 + lr;
    if (c2 < 49) {
      #pragma unroll
      for (int r = 0; r < 4; r++) {
        int f = tmf * 16 + lk * 4 + r;
        if (f < 49) A1[h * 4608 + f * 72 + c2] = (_Float16)(c[r] + ab3[i]);
      }
    }
  }
  // prefetch P5 weight frags + biases + final lin2 operands
  f16x8 wL1[6];
  {
    int tnn = wid & 3;
    #pragma unroll
    for (int ks = 0; ks < 6; ks++)
      wL1[ks] = *(const f16x8*)&ws[30720 + (tnn * 16 + lr) * 192 + ks * 32 + lk * 8];
  }
  float bL1 = (float)ws[100160 + (wid & 3) * 16 + lr];
  float l2wv = 0.f, l2bv = 0.f;
  if (t < 320) { l2wv = P.l2w[(t & 63) * 5 + (t >> 6)]; l2bv = P.l2b[t >> 6]; }
  __syncthreads();

  // ---- softmax: 8 lanes per row, 147 rows; writes K-pad zeros c 49..63 ----
  for (int task = t; task < 1176; task += T) {
    int r = task >> 3, cg = l & 7;
    _Float16* row = A1 + (r / 49) * 4608 + (r - (r / 49) * 49) * 72;
    float vals[8];
    float mx = -1e30f;
    #pragma unroll
    for (int u = 0; u < 8; u++) {
      int c = cg + u * 8;
      float v = (c < 49) ? (float)row[c] : -1e30f;
      vals[u] = v;
      mx = fmaxf(mx, v);
    }
    mx = fmaxf(mx, __shfl_xor(mx, 1, 64));
    mx = fmaxf(mx, __shfl_xor(mx, 2, 64));
    mx = fmaxf(mx, __shfl_xor(mx, 4, 64));
    float s = 0.f;
    #pragma unroll
    for (int u = 0; u < 8; u++) {
      int c = cg + u * 8;
      float e = (c < 49) ? __expf(vals[u] - mx) : 0.f;
      vals[u] = e;
      s += e;
    }
    s += __shfl_xor(s, 1, 64);
    s += __shfl_xor(s, 2, 64);
    s += __shfl_xor(s, 4, 64);
    float inv = 1.f / s;
    #pragma unroll
    for (int u = 0; u < 8; u++) {
      int c = cg + u * 8;
      row[c] = (_Float16)(vals[u] * inv);
    }
  }
  __syncthreads();

  // ---- P4: E = softmax(A1) @ V  (B-op = V^T) -> E [49][200] in sA0 ----
  #pragma unroll
  for (int i = 0; i < 3; i++) {
    int tt = wid + 16 * i;
    int h = tt >> 4, r16 = tt & 15, tmf = r16 >> 2, tnd = r16 & 3;
    f32x4 c = {0.f, 0.f, 0.f, 0.f};
    #pragma unroll
    for (int ks = 0; ks < 2; ks++) {
      f16x8 a  = *(const f16x8*)&A1[h * 4608 + (tmf * 16 + lr) * 72 + ks * 32 + lk * 8];
      f16x8 bvv = *(const f16x8*)&sVT[(h * 64 + tnd * 16 + lr) * 72 + ks * 32 + lk * 8];
      c = MFMA16(a, bvv, c);
    }
    int d = tnd * 16 + lr;
    #pragma unroll
    for (int r = 0; r < 4; r++) {
      int f = tmf * 16 + lk * 4 + r;
      if (f < 49) sA0[f * 200 + h * 64 + d] = (_Float16)c[r];
    }
  }
  __syncthreads();

  // ---- P5: F = relu(E @ l1w + l1b) -> LN -> colmax -> lin2 -> elu ----
  {
    int tmf = wid >> 2;
    f32x4 c = {0.f, 0.f, 0.f, 0.f};
    #pragma unroll
    for (int ks = 0; ks < 6; ks++) {
      f16x8 a = *(const f16x8*)&sA0[(tmf * 16 + lr) * 200 + ks * 32 + lk * 8];
      c = MFMA16(a, wL1[ks], c);
    }
    float* F = (float*)sVT;                       // [49][68] fp32 (V^T dead)
    int n = (wid & 3) * 16 + lr;
    float s8 = 0.f, q8 = 0.f;
    #pragma unroll
    for (int r = 0; r < 4; r++) {
      int f = tmf * 16 + lk * 4 + r;
      if (f < 49) {
        float v = fmaxf(c[r] + bL1, 0.f);
        F[f * 68 + n] = v;
        s8 += v; q8 += v * v;
      }
    }
    block_reduce2(s8, q8, sRed, t);               // first barrier fences F writes
    float m8 = s8 * (1.f / 3136.f);
    float r8 = rsqrtf(q8 * (1.f / 3136.f) - m8 * m8 + EPS);
    float* cm = (float*)sA0;                      // [8][64] partial-max scratch (E dead)
    if (t < 512) {
      int d = t & 63, fg = t >> 6;
      float mx = -1e30f;
      #pragma unroll
      for (int u = 0; u < 7; u++) {
        int f = fg * 7 + u;
        if (f < 49) mx = fmaxf(mx, F[f * 68 + d]);
      }
      cm[fg * 64 + d] = mx;
    }
    __syncthreads();
    if (t < 64) {
      float mx = -1e30f;
      #pragma unroll
      for (int g = 0; g < 8; g++) mx = fmaxf(mx, cm[g * 64 + t]);
      sM[t] = (mx - m8) * r8;                     // rstd > 0: max commutes with normalize
    }
    __syncthreads();
    if (t < 320) {
      float v = sM[t & 63] * l2wv;
      #pragma unroll
      for (int off = 32; off; off >>= 1) v += __shfl_down(v, off, 64);
      if ((t & 63) == 0) P.out[b * 5 + (t >> 6)] = elu_f(v + l2bv);
    }
  }
}

extern "C" void kernel_launch(void* const* d_in, const int* in_sizes, int n_in,
                              void* d_out, int out_size, void* d_ws, size_t ws_size,
                              hipStream_t stream) {
  Params P;
  P.x   = (const float*)d_in[0];
  P.c1w = (const float*)d_in[1];  P.c1b = (const float*)d_in[2];
  P.c2w = (const float*)d_in[3];  P.c2b = (const float*)d_in[4];
  P.kpw = (const float*)d_in[5];  P.kpb = (const float*)d_in[6];
  P.qpw = (const float*)d_in[7];  P.qpb = (const float*)d_in[8];
  P.vpw = (const float*)d_in[9];  P.vpb = (const float*)d_in[10];
  P.kng = (const float*)d_in[11]; P.knb = (const float*)d_in[12];
  P.qng = (const float*)d_in[13]; P.qnb = (const float*)d_in[14];
  P.vng = (const float*)d_in[15]; P.vnb = (const float*)d_in[16];
  P.klw = (const float*)d_in[17]; P.klb = (const float*)d_in[18];
  P.qlw = (const float*)d_in[19]; P.qlb = (const float*)d_in[20];
  P.alw = (const float*)d_in[21]; P.alb = (const float*)d_in[22];
  P.l1w = (const float*)d_in[23]; P.l1b = (const float*)d_in[24];
  P.l2w = (const float*)d_in[25]; P.l2b = (const float*)d_in[26];
  P.out = (float*)d_out;

  _Float16* ws = (_Float16*)d_ws;   // 200448 B used
  hipLaunchKernelGGL(prep_weights, dim3(64), dim3(256), 0, stream, P, ws);

  int B = in_sizes[0] / 147;   // [B,3,7,7]
  hipLaunchKernelGGL(mhr_fused, dim3(B), dim3(T), 0, stream, P, ws);
}

// Round 7
// 413.810 us; speedup vs baseline: 5.4431x; 1.4277x over previous
//
#include <hip/hip_runtime.h>

#define T 512
#define EPS 1e-5f

typedef _Float16 f16x8 __attribute__((ext_vector_type(8)));
typedef _Float16 f16x4 __attribute__((ext_vector_type(4)));
typedef _Float16 f16x2 __attribute__((ext_vector_type(2)));
typedef float f32x4 __attribute__((ext_vector_type(4)));

#define MFMA16(a, b, c) __builtin_amdgcn_mfma_f32_16x16x32_f16((a), (b), (c), 0, 0, 0)
// XOR swizzle on 16-byte blocks within a row: returns f16 offset of block start
#define SWZ8(row, blk) ((((blk) ^ ((row) & 7)) << 3))

struct Params {
  const float *x;
  const float *c1w, *c1b, *c2w, *c2b;
  const float *kpw, *kpb, *qpw, *qpb, *vpw, *vpb;
  const float *kng, *knb, *qng, *qnb, *vng, *vnb;
  const float *klw, *klb, *qlw, *qlb, *alw, *alb;
  const float *l1w, *l1b, *l2w, *l2b;
  float *out;
};

// ws layout (f16 units):
//   0      kpwT [192][32]   (K-pad c 22..31 zeroed)
//   6144   qpwT [192][32]
//   12288  vpwT [192][32]
//   18432  qlwT [64][64]    (rows c>=49 zeroed)
//   22528  klwT [64][64]
//   26624  alwT [64][64]    (rows c2>=49 AND k-cols cA>=49 zeroed)
//   30720  l1wT [64][192]
//   43008  gbKQ [2][49][192][2]  interleaved (gamma,beta), arr0=K arr1=Q
//   80640  gbVT [192][64][2]     interleaved (vng,vnb), zeros for pv>=49
//   105216 bKQ  [192][2]    (kpb,qpb)
//   105600 vpb  [192]
//   105792 cbb  [64]        (qlb+klb, 0 for c>=49)
//   105856 alb  [64]        (0 for c>=49)
//   105920 l1b  [64]
// total 105984 f16 = 211968 B
__global__ __launch_bounds__(256) void prep_weights(Params P, _Float16* ws) {
  int t0 = blockIdx.x * 256 + threadIdx.x;
  int stride = gridDim.x * 256;
  for (int i = t0; i < 3 * 6144; i += stride) {
    int pr = i / 6144, r = i - pr * 6144;
    int j = r >> 5, c = r & 31;
    const float* w = pr == 0 ? P.kpw : pr == 1 ? P.qpw : P.vpw;
    ws[i] = (c < 22) ? (_Float16)w[c * 192 + j] : (_Float16)0.f;
  }
  for (int i = t0; i < 2 * 4096; i += stride) {
    int pr = i >> 12, r = i & 4095;
    int c = r >> 6, d = r & 63;
    const float* w = pr == 0 ? P.qlw : P.klw;
    ws[18432 + i] = (c < 49) ? (_Float16)w[d * 49 + c] : (_Float16)0.f;
  }
  for (int i = t0; i < 4096; i += stride) {
    int c2 = i >> 6, cA = i & 63;
    ws[26624 + i] = (c2 < 49 && cA < 49) ? (_Float16)P.alw[cA * 49 + c2] : (_Float16)0.f;
  }
  for (int i = t0; i < 12288; i += stride) {
    int n = i / 192, k = i - n * 192;
    ws[30720 + i] = (_Float16)P.l1w[k * 64 + n];
  }
  for (int i = t0; i < 2 * 49 * 192; i += stride) {   // gbKQ
    int arr = i / 9408, rem = i - arr * 9408;
    int p = rem / 192, j = rem - p * 192;
    int gi = ((j >> 6) * 49 + p) * 64 + (j & 63);
    const float* g  = arr ? P.qng : P.kng;
    const float* bb = arr ? P.qnb : P.knb;
    ws[43008 + i * 2]     = (_Float16)g[gi];
    ws[43008 + i * 2 + 1] = (_Float16)bb[gi];
  }
  for (int i = t0; i < 12288; i += stride) {          // gbVT
    int j = i >> 6, pv = i & 63;
    if (pv < 49) {
      int gi = ((j >> 6) * 49 + pv) * 64 + (j & 63);
      ws[80640 + i * 2]     = (_Float16)P.vng[gi];
      ws[80640 + i * 2 + 1] = (_Float16)P.vnb[gi];
    } else {
      ws[80640 + i * 2]     = (_Float16)0.f;
      ws[80640 + i * 2 + 1] = (_Float16)0.f;
    }
  }
  for (int i = t0; i < 192; i += stride) {
    ws[105216 + i * 2]     = (_Float16)P.kpb[i];
    ws[105216 + i * 2 + 1] = (_Float16)P.qpb[i];
    ws[105600 + i]         = (_Float16)P.vpb[i];
  }
  for (int i = t0; i < 64; i += stride) {
    ws[105792 + i] = (i < 49) ? (_Float16)(P.qlb[i] + P.klb[i]) : (_Float16)0.f;
    ws[105856 + i] = (i < 49) ? (_Float16)P.alb[i] : (_Float16)0.f;
    ws[105920 + i] = (_Float16)P.l1b[i];
  }
}

__device__ inline float elu_f(float v) { return v > 0.f ? v : __expf(v) - 1.f; }

// block-wide reduce of 6 sums for 8 waves; all threads get totals.
__device__ inline void block_reduce6(float* v, float* sRed, int t) {
  int lane = t & 63, wid = t >> 6;   // wid 0..7
  #pragma unroll
  for (int k = 0; k < 6; k++) {
    float x = v[k];
    #pragma unroll
    for (int off = 32; off; off >>= 1) x += __shfl_down(x, off, 64);
    if (lane == 0) sRed[k * 8 + wid] = x;
  }
  __syncthreads();
  if (t < 6) {
    float s = 0.f;
    #pragma unroll
    for (int w = 0; w < 8; w++) s += sRed[t * 8 + w];
    sRed[t * 8] = s;
  }
  __syncthreads();
  #pragma unroll
  for (int k = 0; k < 6; k++) v[k] = sRed[k * 8];
}

__device__ inline void block_reduce2(float& sum, float& sq, float* sRed, int t) {
  int lane = t & 63, wid = t >> 6;
  #pragma unroll
  for (int off = 32; off; off >>= 1) {
    sum += __shfl_down(sum, off, 64);
    sq  += __shfl_down(sq,  off, 64);
  }
  if (lane == 0) { sRed[wid] = sum; sRed[8 + wid] = sq; }
  __syncthreads();
  if (t == 0) {
    float s = 0.f, q = 0.f;
    #pragma unroll
    for (int w = 0; w < 8; w++) { s += sRed[w]; q += sRed[8 + w]; }
    sRed[0] = s; sRed[8] = q;
  }
  __syncthreads();
  sum = sRed[0]; sq = sRed[8];
}

// MFMA fragment conventions (16x16x32, fp16 in / fp32 out):
//   A-frag: lane l holds A[row = l&15][k = (l>>4)*8 + e]           ([M][K] row-major)
//   B-frag: lane l holds B[k = (l>>4)*8 + e][col = l&15]           (from BT[N][K] row-major)
//   C/D  : lane l, reg r -> D[row = (l>>4)*4 + r][col = l&15]
// All big LDS tiles use the SWZ8 16-B-block XOR swizzle (<=2-way bank aliasing,
// which is free), enabling minimal strides so total LDS = 81536 B -> 2 blocks/CU.

__global__ __launch_bounds__(T, 4) void mhr_fused(Params P, const _Float16* __restrict__ ws) {
  const int b = blockIdx.x;
  const int t = threadIdx.x;
  const int wid = t >> 6, l = t & 63, lr = l & 15, lk = l >> 4;

  __shared__ __align__(16) _Float16 sKQ[18816];  // K[49][192], Q at +9408 (swz); later A1[3][49][64] (swz)
  __shared__ __align__(16) _Float16 sA0[9408];   // sTok[64][40]; A0[3][49][64] (swz); E[49][192] (swz); cm f32[8][64]
  __shared__ __align__(16) _Float16 sVT[12288];  // P0 f32 scratch; V^T[192][64] (swz); F f32[49][68]
  __shared__ float sRed[64];
  __shared__ float sM[64];

  _Float16* sTok = sA0;            // [64][40], dead after P1-A; A0 written in P2

  // ---- zero sTok (rows>=49 and K-pad cols 22..39 must be 0) ----
  for (int i = t; i < 1280; i += T) ((unsigned*)sTok)[i] = 0u;

  // ---- P0: x -> tokens as fp16 A-tile [64][40] ----
  float* xb = (float*)sVT;         // 147 floats (dead before V^T written)
  float* h1 = (float*)sVT + 160;   // 784 floats
  for (int i = t; i < 147; i += T) xb[i] = P.x[b * 147 + i];
  __syncthreads();
  for (int i = t; i < 784; i += T) {
    int p = i >> 4, o = i & 15;
    float a = P.c1b[o] + xb[p] * P.c1w[o * 3] + xb[49 + p] * P.c1w[o * 3 + 1]
            + xb[98 + p] * P.c1w[o * 3 + 2];
    h1[p * 16 + o] = fmaxf(a, 0.f);
  }
  __syncthreads();
  for (int i = t; i < 980; i += T) {
    int p = i / 20, o = i - p * 20;
    float a = P.c2b[o];
    #pragma unroll
    for (int c = 0; c < 16; c++) a += h1[p * 16 + c] * P.c2w[o * 16 + c];
    sTok[p * 40 + o] = (_Float16)fmaxf(a, 0.f);
  }
  for (int i = t; i < 49; i += T) {
    sTok[i * 40 + 20] = (_Float16)((float)(i % 7) * (1.f / 7.f));
    sTok[i * 40 + 21] = (_Float16)((float)(i / 7) * (1.f / 7.f));
  }
  __syncthreads();

  // ---- P1-A: K/Q/V projections, RAW f16 to LDS + stats ----
  float st[6] = {0.f, 0.f, 0.f, 0.f, 0.f, 0.f};
  #pragma unroll
  for (int i = 0; i < 6; i++) {
    int tt = wid + 8 * i;
    int tm = tt / 12, tn = tt - tm * 12;          // K/Q: D[p][j], 4x12 tiles
    f16x8 a  = *(const f16x8*)&sTok[(tm * 16 + lr) * 40 + lk * 8];
    f16x8 bK = *(const f16x8*)&ws[(tn * 16 + lr) * 32 + lk * 8];
    f16x8 bQ = *(const f16x8*)&ws[6144 + (tn * 16 + lr) * 32 + lk * 8];
    f32x4 z = {0.f, 0.f, 0.f, 0.f};
    f32x4 k4 = MFMA16(a, bK, z);
    f32x4 q4 = MFMA16(a, bQ, z);
    f16x2 b2 = *(const f16x2*)&ws[105216 + (tn * 16 + lr) * 2];
    int j = tn * 16 + lr;
    #pragma unroll
    for (int r = 0; r < 4; r++) {
      int p = tm * 16 + lk * 4 + r;
      float vk = k4[r] + (float)b2.x, vq = q4[r] + (float)b2.y;
      if (p < 49) {
        st[0] += vk; st[1] += vk * vk; st[2] += vq; st[3] += vq * vq;
        int idx = p * 192 + SWZ8(p, j >> 3) + (j & 7);
        sKQ[idx] = (_Float16)vk;
        sKQ[9408 + idx] = (_Float16)vq;
      }
    }
    int vm = tt >> 2, vn = tt & 3;                // V^T: D[j][p], 12x4 tiles, swapped ops
    f16x8 av = *(const f16x8*)&ws[12288 + (vm * 16 + lr) * 32 + lk * 8];
    f16x8 bt = *(const f16x8*)&sTok[(vn * 16 + lr) * 40 + lk * 8];
    f32x4 v4 = MFMA16(av, bt, z);
    f16x4 vb4 = *(const f16x4*)&ws[105600 + vm * 16 + lk * 4];
    int pv = vn * 16 + lr;
    #pragma unroll
    for (int r = 0; r < 4; r++) {
      int j2 = vm * 16 + lk * 4 + r;
      float vv = v4[r] + (float)vb4[r];
      if (pv < 49) { st[4] += vv; st[5] += vv * vv; }
      sVT[j2 * 64 + SWZ8(j2, pv >> 3) + (pv & 7)] = (_Float16)vv;  // pads fixed by normalize
    }
  }
  block_reduce6(st, sRed, t);   // 2 barriers: fence raw writes
  float muK = st[0] * (1.f / 9408.f), rrK = rsqrtf(st[1] * (1.f / 9408.f) - muK * muK + EPS);
  float muQ = st[2] * (1.f / 9408.f), rrQ = rsqrtf(st[3] * (1.f / 9408.f) - muQ * muQ + EPS);
  float muV = st[4] * (1.f / 9408.f), rrV = rsqrtf(st[5] * (1.f / 9408.f) - muV * muV + EPS);

  // ---- P1-B: vectorized in-place LN (gamma/beta interleaved packs from ws) ----
  for (int task = t; task < 2352; task += T) {   // K/Q: 2 arr x 49 p x 24 blk
    int arr = task / 1176, rem = task - arr * 1176;
    int p = rem / 24, blk = rem - p * 24;
    int off = arr * 9408 + p * 192 + SWZ8(p, blk);
    f16x8 raw = *(const f16x8*)&sKQ[off];
    const _Float16* gb = &ws[43008 + ((arr * 49 + p) * 192 + blk * 8) * 2];
    f16x8 g0 = *(const f16x8*)gb;
    f16x8 g1 = *(const f16x8*)(gb + 8);
    float mu = arr ? muQ : muK, rr = arr ? rrQ : rrK;
    f16x8 o8;
    #pragma unroll
    for (int e = 0; e < 8; e++) {
      float g  = (float)(e < 4 ? g0[e * 2]     : g1[(e - 4) * 2]);
      float bb = (float)(e < 4 ? g0[e * 2 + 1] : g1[(e - 4) * 2 + 1]);
      o8[e] = (_Float16)(((float)raw[e] - mu) * rr * g + bb);
    }
    *(f16x8*)&sKQ[off] = o8;
  }
  for (int task = t; task < 1536; task += T) {   // V^T: 192 j x 8 blk (pads -> 0 via gbVT)
    int j = task >> 3, blk = task & 7;
    int off = j * 64 + SWZ8(j, blk);
    f16x8 raw = *(const f16x8*)&sVT[off];
    const _Float16* gb = &ws[80640 + (j * 64 + blk * 8) * 2];
    f16x8 g0 = *(const f16x8*)gb;
    f16x8 g1 = *(const f16x8*)(gb + 8);
    f16x8 o8;
    #pragma unroll
    for (int e = 0; e < 8; e++) {
      float g  = (float)(e < 4 ? g0[e * 2]     : g1[(e - 4) * 2]);
      float bb = (float)(e < 4 ? g0[e * 2 + 1] : g1[(e - 4) * 2 + 1]);
      o8[e] = (_Float16)(((float)raw[e] - muV) * rrV * g + bb);
    }
    *(f16x8*)&sVT[off] = o8;
  }
  __syncthreads();

  // ---- P2: A0 = elu(Qn@qlw + Kn@klw + bias) ----
  #pragma unroll
  for (int i = 0; i < 6; i++) {
    int tt = wid + 8 * i;
    int h = tt >> 4, r16 = tt & 15, tmf = r16 >> 2, tnc = r16 & 3;
    int row = tmf * 16 + lr;
    f32x4 c = {0.f, 0.f, 0.f, 0.f};
    #pragma unroll
    for (int ks = 0; ks < 2; ks++) {
      int ablk = h * 8 + ks * 4 + lk;
      f16x8 aQ = *(const f16x8*)&sKQ[9408 + row * 192 + SWZ8(row, ablk)];
      f16x8 bQ = *(const f16x8*)&ws[18432 + (tnc * 16 + lr) * 64 + ks * 32 + lk * 8];
      c = MFMA16(aQ, bQ, c);
      f16x8 aK = *(const f16x8*)&sKQ[row * 192 + SWZ8(row, ablk)];
      f16x8 bK = *(const f16x8*)&ws[22528 + (tnc * 16 + lr) * 64 + ks * 32 + lk * 8];
      c = MFMA16(aK, bK, c);
    }
    int cc = tnc * 16 + lr;
    float cb = (float)ws[105792 + cc];
    #pragma unroll
    for (int r = 0; r < 4; r++) {
      int f = tmf * 16 + lk * 4 + r;
      if (f < 49)
        sA0[h * 3136 + f * 64 + SWZ8(f, cc >> 3) + (cc & 7)] =
            (cc < 49) ? (_Float16)elu_f(c[r] + cb) : (_Float16)0.f;
    }
  }
  __syncthreads();

  // ---- P3: A1 = A0 @ alw + alb -> sKQ region (K/Q dead) ----
  _Float16* A1 = sKQ;
  #pragma unroll
  for (int i = 0; i < 6; i++) {
    int tt = wid + 8 * i;
    int h = tt >> 4, r16 = tt & 15, tmf = r16 >> 2, tnc = r16 & 3;
    int row = tmf * 16 + lr;
    f32x4 c = {0.f, 0.f, 0.f, 0.f};
    #pragma unroll
    for (int ks = 0; ks < 2; ks++) {
      f16x8 a = *(const f16x8*)&sA0[h * 3136 + row * 64 + SWZ8(row, ks * 4 + lk)];
      f16x8 bf = *(const f16x8*)&ws[26624 + (tnc * 16 + lr) * 64 + ks * 32 + lk * 8];
      c = MFMA16(a, bf, c);
    }
    int c2 = tnc * 16 + lr;
    float ab = (float)ws[105856 + c2];
    if (c2 < 49) {
      #pragma unroll
      for (int r = 0; r < 4; r++) {
        int f = tmf * 16 + lk * 4 + r;
        if (f < 49) A1[h * 3136 + f * 64 + SWZ8(f, c2 >> 3) + (c2 & 7)] = (_Float16)(c[r] + ab);
      }
    }
  }
  __syncthreads();

  // ---- softmax: 8 lanes per row; writes K-pad zeros c 49..63 ----
  for (int task = t; task < 1176; task += T) {
    int r_ = task >> 3, cg = task & 7;
    int hh = r_ / 49, f = r_ - hh * 49;
    _Float16* rowp = A1 + hh * 3136 + f * 64;
    float vals[8];
    float mx = -1e30f;
    #pragma unroll
    for (int u = 0; u < 8; u++) {
      int c = cg + u * 8;
      float v = (c < 49) ? (float)rowp[SWZ8(f, u) + cg] : -1e30f;
      vals[u] = v;
      mx = fmaxf(mx, v);
    }
    mx = fmaxf(mx, __shfl_xor(mx, 1, 64));
    mx = fmaxf(mx, __shfl_xor(mx, 2, 64));
    mx = fmaxf(mx, __shfl_xor(mx, 4, 64));
    float s = 0.f;
    #pragma unroll
    for (int u = 0; u < 8; u++) {
      int c = cg + u * 8;
      float e = (c < 49) ? __expf(vals[u] - mx) : 0.f;
      vals[u] = e;
      s += e;
    }
    s += __shfl_xor(s, 1, 64);
    s += __shfl_xor(s, 2, 64);
    s += __shfl_xor(s, 4, 64);
    float inv = 1.f / s;
    #pragma unroll
    for (int u = 0; u < 8; u++) rowp[SWZ8(f, u) + cg] = (_Float16)(vals[u] * inv);
  }
  __syncthreads();

  // ---- P4: E = softmax(A1) @ V (B-op = V^T) -> E [49][192] swz in sA0 ----
  #pragma unroll
  for (int i = 0; i < 6; i++) {
    int tt = wid + 8 * i;
    int h = tt >> 4, r16 = tt & 15, tmf = r16 >> 2, tnd = r16 & 3;
    int row = tmf * 16 + lr;
    int vrow = h * 64 + tnd * 16 + lr;
    f32x4 c = {0.f, 0.f, 0.f, 0.f};
    #pragma unroll
    for (int ks = 0; ks < 2; ks++) {
      f16x8 a  = *(const f16x8*)&A1[h * 3136 + row * 64 + SWZ8(row, ks * 4 + lk)];
      f16x8 bv = *(const f16x8*)&sVT[vrow * 64 + SWZ8(vrow, ks * 4 + lk)];
      c = MFMA16(a, bv, c);
    }
    int col = h * 64 + tnd * 16 + lr;
    #pragma unroll
    for (int r = 0; r < 4; r++) {
      int f = tmf * 16 + lk * 4 + r;
      if (f < 49) sA0[f * 192 + SWZ8(f, col >> 3) + (col & 7)] = (_Float16)c[r];
    }
  }
  __syncthreads();

  // ---- P5: F = relu(E @ l1w + l1b) -> LN -> colmax -> lin2 -> elu ----
  float* F = (float*)sVT;          // [49][68] fp32 (V^T dead)
  float s8 = 0.f, q8 = 0.f;
  #pragma unroll
  for (int i = 0; i < 2; i++) {
    int tile = wid + 8 * i;
    int tmf = tile >> 2, tnn = tile & 3;
    int row = tmf * 16 + lr;
    f32x4 c = {0.f, 0.f, 0.f, 0.f};
    #pragma unroll
    for (int ks = 0; ks < 6; ks++) {
      f16x8 a  = *(const f16x8*)&sA0[row * 192 + SWZ8(row, ks * 4 + lk)];
      f16x8 bf = *(const f16x8*)&ws[30720 + (tnn * 16 + lr) * 192 + ks * 32 + lk * 8];
      c = MFMA16(a, bf, c);
    }
    int n = tnn * 16 + lr;
    float bn = (float)ws[105920 + n];
    #pragma unroll
    for (int r = 0; r < 4; r++) {
      int f = tmf * 16 + lk * 4 + r;
      if (f < 49) {
        float v = fmaxf(c[r] + bn, 0.f);
        F[f * 68 + n] = v;
        s8 += v; q8 += v * v;
      }
    }
  }
  block_reduce2(s8, q8, sRed, t);  // first barrier fences F writes + all E reads
  float m8 = s8 * (1.f / 3136.f);
  float r8 = rsqrtf(q8 * (1.f / 3136.f) - m8 * m8 + EPS);
  float* cm = (float*)sA0;         // [8][64] partial colmax (E dead after barrier)
  {
    int d = t & 63, fg = t >> 6;
    float mx = -1e30f;
    #pragma unroll
    for (int u = 0; u < 7; u++) {
      int f = fg * 7 + u;
      if (f < 49) mx = fmaxf(mx, F[f * 68 + d]);
    }
    cm[fg * 64 + d] = mx;
  }
  __syncthreads();
  if (t < 64) {
    float mx = -1e30f;
    #pragma unroll
    for (int g = 0; g < 8; g++) mx = fmaxf(mx, cm[g * 64 + t]);
    sM[t] = (mx - m8) * r8;        // rstd > 0: max commutes with normalize
  }
  __syncthreads();
  if (t < 320) {
    float v = sM[t & 63] * P.l2w[(t & 63) * 5 + (t >> 6)];
    #pragma unroll
    for (int off = 32; off; off >>= 1) v += __shfl_down(v, off, 64);
    if ((t & 63) == 0) P.out[b * 5 + (t >> 6)] = elu_f(v + P.l2b[t >> 6]);
  }
}

extern "C" void kernel_launch(void* const* d_in, const int* in_sizes, int n_in,
                              void* d_out, int out_size, void* d_ws, size_t ws_size,
                              hipStream_t stream) {
  Params P;
  P.x   = (const float*)d_in[0];
  P.c1w = (const float*)d_in[1];  P.c1b = (const float*)d_in[2];
  P.c2w = (const float*)d_in[3];  P.c2b = (const float*)d_in[4];
  P.kpw = (const float*)d_in[5];  P.kpb = (const float*)d_in[6];
  P.qpw = (const float*)d_in[7];  P.qpb = (const float*)d_in[8];
  P.vpw = (const float*)d_in[9];  P.vpb = (const float*)d_in[10];
  P.kng = (const float*)d_in[11]; P.knb = (const float*)d_in[12];
  P.qng = (const float*)d_in[13]; P.qnb = (const float*)d_in[14];
  P.vng = (const float*)d_in[15]; P.vnb = (const float*)d_in[16];
  P.klw = (const float*)d_in[17]; P.klb = (const float*)d_in[18];
  P.qlw = (const float*)d_in[19]; P.qlb = (const float*)d_in[20];
  P.alw = (const float*)d_in[21]; P.alb = (const float*)d_in[22];
  P.l1w = (const float*)d_in[23]; P.l1b = (const float*)d_in[24];
  P.l2w = (const float*)d_in[25]; P.l2b = (const float*)d_in[26];
  P.out = (float*)d_out;

  _Float16* ws = (_Float16*)d_ws;   // 211968 B used
  hipLaunchKernelGGL(prep_weights, dim3(64), dim3(256), 0, stream, P, ws);

  int B = in_sizes[0] / 147;   // [B,3,7,7]
  hipLaunchKernelGGL(mhr_fused, dim3(B), dim3(T), 0, stream, P, ws);
}